// Round 7
// baseline (397.680 us; speedup 1.0000x reference)
//
#include <hip/hip_runtime.h>
#include <cstdint>
#include <math.h>

typedef _Float16 half_t;
typedef __attribute__((ext_vector_type(8))) _Float16 half8;
typedef __attribute__((ext_vector_type(4))) float floatx4;

// ---------------- workspace byte layout ----------------
// bbwh   @ 0            12,582,912   fp16 [32 nt][96 s][4 kg][64 n][16B]
// zpad   @ 12,582,912   1,024
// topidx @ 12,583,936   1,024
// scores @ 12,584,960   103,424
// y1     @ 12,688,384   1,605,632
// y2     @ 14,294,016   401,408
// y3     @ 14,695,424   131,072
// concat @ 14,826,496   655,360
// w1h    @ 15,481,856   4,718,592    fp16 [9 tap][64 s][4 kg][128 n][16B]
// wt2t   @ 20,200,448   589,824
// wt3t   @ 20,790,272   589,824
// E      @ 21,380,096   39,321,600:  phase1 xh / phase2 y1p
// F      @ 60,701,696:  phase1 rawh fp16 (+64 pad rows spill, still in F) / phase2 abar fp32
// end 86,391,808

typedef __attribute__((address_space(3))) unsigned int lds_u32;
typedef const __attribute__((address_space(1))) unsigned int glb_u32;
__device__ __forceinline__ void glds16(const void* g, void* l) {
    __builtin_amdgcn_global_load_lds((glb_u32*)g, (lds_u32*)l, 16, 0, 0);
}

// ================= prep_all =================
__global__ __launch_bounds__(256)
void prep_all(const float* __restrict__ x, const float* __restrict__ bbw,
              const float* __restrict__ n1dw, const float* __restrict__ n2dw,
              const float* __restrict__ n3dw, const float* __restrict__ cnb,
              const float* __restrict__ bbb,
              half_t* __restrict__ xh,
              half_t* __restrict__ bh, half_t* __restrict__ w1h,
              float* __restrict__ wt2t, float* __restrict__ wt3t,
              float* __restrict__ out, float* __restrict__ zpad,
              float* __restrict__ concat)
{
    const int t = blockIdx.x * 256 + threadIdx.x;
    if (t < 307200) {
        const int m = t % 3200, s = t / 3200;
        const int mt = m >> 7, mr = m & 127;
        float f[32];
        if (m < 3136) {
            const int bq = m / 196, pos = m % 196, oy = pos / 14, ox = pos % 14;
            const int c = s >> 5, r = s & 31;
            const float* p = x + ((size_t)(bq * 3 + c) * 448 + oy * 32 + r) * 448 + ox * 32;
            #pragma unroll
            for (int i = 0; i < 8; ++i) *(float4*)&f[i * 4] = *(const float4*)(p + i * 4);
        } else {
            #pragma unroll
            for (int j = 0; j < 32; ++j) f[j] = 0.f;
        }
        #pragma unroll
        for (int kg = 0; kg < 4; ++kg) {
            half8 h;
            #pragma unroll
            for (int j = 0; j < 8; ++j) h[j] = (half_t)f[kg * 8 + j];
            const size_t dst = (((size_t)(mt * 96 + s) * 4 + kg) * 128 + mr) * 8;
            *(half8*)(xh + dst) = h;
        }
    } else if (t < 503808) {
        const int t2 = t - 307200;
        const int n = t2 & 2047, s = t2 >> 11;
        const float* p = bbw + (size_t)n * 3072 + s * 32;
        float f[32];
        #pragma unroll
        for (int i = 0; i < 8; ++i) *(float4*)&f[i * 4] = *(const float4*)(p + i * 4);
        const int nt = n >> 6, nr = n & 63;
        #pragma unroll
        for (int kg = 0; kg < 4; ++kg) {
            half8 h;
            #pragma unroll
            for (int j = 0; j < 8; ++j) h[j] = (half_t)f[kg * 8 + j];
            const size_t dst = (((size_t)(nt * 96 + s) * 4 + kg) * 64 + nr) * 8;
            *(half8*)(bh + dst) = h;
        }
    } else if (t < 536576) {
        const int t2 = t - 503808;
        const int n = t2 >> 8, ic8 = t2 & 255;
        const int s = ic8 >> 2, kg = ic8 & 3;
        const float* src = n1dw + ((size_t)n * 2048 + ic8 * 8) * 9;
        float buf[72];
        #pragma unroll
        for (int i = 0; i < 18; ++i) *(float4*)&buf[i * 4] = *(const float4*)(src + i * 4);
        #pragma unroll
        for (int tap = 0; tap < 9; ++tap) {
            half8 h;
            #pragma unroll
            for (int j = 0; j < 8; ++j) h[j] = (half_t)buf[j * 9 + tap];
            const size_t dst = (((size_t)(tap * 64 + s) * 4 + kg) * 128 + n) * 8;
            *(half8*)(w1h + dst) = h;
        }
    } else if (t < 684032) {
        const int t2 = t - 536576;
        const int oc = t2 % 128, rest = t2 / 128, ic = rest % 128, tap = rest / 128;
        wt2t[(tap * 128 + ic) * 128 + oc] = n2dw[((size_t)oc * 128 + ic) * 9 + tap];
    } else if (t < 831488) {
        const int t2 = t - 684032;
        const int oc = t2 % 128, rest = t2 / 128, ic = rest % 128, tap = rest / 128;
        wt3t[(tap * 128 + ic) * 128 + oc] = n3dw[((size_t)oc * 128 + ic) * 9 + tap];
    } else if (t < 834688) {
        const int i = t - 831488;
        out[i] = cnb[i % 200];
    } else if (t < 834944) {
        zpad[t - 834688] = 0.f;
    } else if (t < 998784) {
        const int i = t - 834944;
        const int r = i % 10240;
        concat[i] = (r < 8192) ? bbb[r & 2047] : 0.f;
    }
}

// ====== gemm_x: fp16 64Mx128N, BK=64, 4 waves (each 32Mx64N), XCD nt-slab swizzle ======
// A direct-to-register (4 loads/wave/step), B double-buffered LDS:
// each B ds_read feeds 2 MFMAs. Counted vmcnt(8), raw barriers.
__global__ __launch_bounds__(256)
void gemm_x(const half_t* __restrict__ Ah, const half_t* __restrict__ Bh,
            const float* __restrict__ bias, half_t* __restrict__ outh)
{
    __shared__ __align__(16) char L[32768]; // 2 x 16KB B: [ki2][nh2][kg4][64n][16B]
    const int tid = threadIdx.x, lane = tid & 63, wv = tid >> 6;
    // XCD slab: 784 blocks = 8 XCD x (2 nt x 49 mt). Intra-XCD: consecutive
    // blocks share the mt A-tile; B slab = 2 panels = 1.57MB (L2-resident).
    const int bid = blockIdx.y * 16 + blockIdx.x;
    const int xcd = bid & 7, ii = bid >> 3;      // ii in [0,98)
    const int nt = 2 * xcd + (ii & 1), mt = ii >> 1;
    const int lm = lane & 15, quad = lane >> 4;
    const int wr = wv >> 1, wc = wv & 1;         // wave = (M-half, N-half)

    // A per-lane: frag(mi,ki,s) = pA + s*16384 + ki*8192 + mi*256
    const char* pA = (const char*)Ah + (size_t)(mt >> 1) * 786432
                   + quad * 2048 + ((mt & 1) * 64 + wr * 32 + lm) * 16;

    // B staging: wave wv stages (kiw=wv>>1, nhw=wv&1), kg=0..3 (4 x 1KB)
    const int kiw = wv >> 1, nhw = wv & 1;
    const char* gBp = (const char*)Bh + (size_t)(2 * nt + nhw) * 393216 + lane * 16;
    const int lB = kiw * 8192 + nhw * 4096;

    // B read: frag(ki,jl) = Lc + ki*8192 + wc*4096 + quad*1024 + (jl*16+lm)*16
    const int brd = wc * 4096 + quad * 1024 + lm * 16;

    floatx4 acc[2][4];
    const floatx4 fz = {0.f, 0.f, 0.f, 0.f};
    #pragma unroll
    for (int mi = 0; mi < 2; ++mi)
        #pragma unroll
        for (int j = 0; j < 4; ++j) acc[mi][j] = fz;

    half8 c00, c01, c10, c11, n00, n01, n10, n11; // a[mi][ki]

    // prologue: stage B(0) -> buf0 (4 glds/wave) + A(0) (4 loads) = 8 outstanding
    #pragma unroll
    for (int kg = 0; kg < 4; ++kg)
        glds16(gBp + (size_t)kiw * 4096 + kg * 1024, L + lB + kg * 1024);
    c00 = *(const half8*)(pA);
    c01 = *(const half8*)(pA + 8192);
    c10 = *(const half8*)(pA + 256);
    c11 = *(const half8*)(pA + 8192 + 256);

    auto step = [&](int sn, const char* Lc, char* Ln,
                    half8& a00, half8& a01, half8& a10, half8& a11,
                    half8& b00, half8& b01, half8& b10, half8& b11) {
        #pragma unroll
        for (int kg = 0; kg < 4; ++kg)
            glds16(gBp + (size_t)(2 * sn + kiw) * 4096 + kg * 1024, Ln + lB + kg * 1024);
        const char* pAs = pA + (size_t)sn * 16384;
        b00 = *(const half8*)(pAs);
        b01 = *(const half8*)(pAs + 8192);
        b10 = *(const half8*)(pAs + 256);
        b11 = *(const half8*)(pAs + 8192 + 256);
        asm volatile("s_waitcnt vmcnt(8)" ::: "memory");
        __builtin_amdgcn_s_barrier();
        __builtin_amdgcn_sched_barrier(0);
        #pragma unroll
        for (int ki = 0; ki < 2; ++ki) {
            const half8 a0 = ki ? a01 : a00;
            const half8 a1 = ki ? a11 : a10;
            #pragma unroll
            for (int j = 0; j < 4; ++j) {
                half8 b = *(const half8*)(Lc + ki * 8192 + brd + j * 256);
                acc[0][j] = __builtin_amdgcn_mfma_f32_16x16x32_f16(a0, b, acc[0][j], 0, 0, 0);
                acc[1][j] = __builtin_amdgcn_mfma_f32_16x16x32_f16(a1, b, acc[1][j], 0, 0, 0);
            }
        }
        __builtin_amdgcn_sched_barrier(0);
        __builtin_amdgcn_s_barrier();
    };

    for (int h = 0; h < 24; ++h) {
        const int s1 = 2 * h + 1;
        step(s1, L, L + 16384, c00, c01, c10, c11, n00, n01, n10, n11);
        step((s1 < 47) ? s1 + 1 : 0, L + 16384, L, n00, n01, n10, n11, c00, c01, c10, c11);
    }

    #pragma unroll
    for (int j = 0; j < 4; ++j) {
        const int n = nt * 128 + wc * 64 + j * 16 + lm;
        const float bv = bias[n];
        #pragma unroll
        for (int mi = 0; mi < 2; ++mi) {
            const int m0 = mt * 64 + wr * 32 + mi * 16 + quad * 4;
            #pragma unroll
            for (int r = 0; r < 4; ++r)
                outh[(size_t)(m0 + r) * 2048 + n] = (half_t)(acc[mi][j][r] + bv);
        }
    }
}

// ====== gemm_nav: fp16 64Mx128N, BK=64, 4 waves (each 32Mx64N), tx-slab swizzle ======
__global__ __launch_bounds__(256)
void gemm_nav(const half_t* __restrict__ rawh, const half_t* __restrict__ Bh,
              const char* __restrict__ zpad, float* __restrict__ y1p)
{
    __shared__ __align__(16) char L[32768]; // 2 x 16KB B: [ki2][kg4][128n][16B]
    const int tid = threadIdx.x, lane = tid & 63, wv = tid >> 6;
    // bijective XCD slab (882 = 2x111 + 6x110), tx-major within slab
    const int bid = blockIdx.y * 18 + blockIdx.x;
    const int xcd = bid & 7, ii = bid >> 3;
    const int Lx = (xcd < 2 ? xcd * 111 : 222 + (xcd - 2) * 110) + ii;
    const int tx = Lx / 49, mt = Lx % 49;
    const int tap = tx >> 1, ks = tx & 1;
    const int lm = lane & 15, quad = lane >> 4;
    const int wr = wv >> 1, wc = wv & 1;

    // per-mi A row pointers (halo -> zpad); frag(mi,ki,sn) = fb_mi + fs_mi*(sn*128 + ki*64 + quad*16)
    const char* fb0; const char* fb1; int fs0, fs1;
    {
        const int g0 = mt * 64 + wr * 32 + lm;
        const int b = g0 / 196, pos = g0 % 196, oy = pos / 14, ox = pos % 14;
        const int iy = oy + tap / 3 - 1, ix = ox + tap % 3 - 1;
        const bool av = (iy >= 0 && iy < 14 && ix >= 0 && ix < 14);
        fb0 = av ? (const char*)rawh + ((size_t)(b * 196 + iy * 14 + ix)) * 4096 + ks * 2048 : zpad;
        fs0 = av ? 1 : 0;
    }
    {
        const int g1 = mt * 64 + wr * 32 + 16 + lm;
        const int b = g1 / 196, pos = g1 % 196, oy = pos / 14, ox = pos % 14;
        const int iy = oy + tap / 3 - 1, ix = ox + tap % 3 - 1;
        const bool av = (iy >= 0 && iy < 14 && ix >= 0 && ix < 14);
        fb1 = av ? (const char*)rawh + ((size_t)(b * 196 + iy * 14 + ix)) * 4096 + ks * 2048 : zpad;
        fs1 = av ? 1 : 0;
    }

    // B staging: wave wv -> kiw=wv>>1, kgh=wv&1; 4 x 1KB chunks
    const int kiw = wv >> 1, kgh = wv & 1;
    const char* gB = (const char*)Bh + (size_t)tap * 524288 + (size_t)(ks * 32) * 8192 + lane * 16;
    int cof[4];
    #pragma unroll
    for (int t = 0; t < 4; ++t)
        cof[t] = (kgh * 2 + (t >> 1)) * 2048 + (t & 1) * 1024;

    // B read: frag(ki,jl) = Lc + ki*8192 + quad*2048 + (wc*64 + jl*16 + lm)*16
    const int brd = quad * 2048 + (wc * 64 + lm) * 16;

    floatx4 acc[2][4];
    const floatx4 fz = {0.f, 0.f, 0.f, 0.f};
    #pragma unroll
    for (int mi = 0; mi < 2; ++mi)
        #pragma unroll
        for (int j = 0; j < 4; ++j) acc[mi][j] = fz;

    half8 c00, c01, c10, c11, n00, n01, n10, n11;

    // prologue: stage B(0) -> buf0, A(0)  (8 outstanding/wave)
    #pragma unroll
    for (int t = 0; t < 4; ++t)
        glds16(gB + (size_t)kiw * 8192 + cof[t], L + kiw * 8192 + cof[t]);
    c00 = *(const half8*)(fb0 + fs0 * (quad * 16));
    c01 = *(const half8*)(fb0 + fs0 * (64 + quad * 16));
    c10 = *(const half8*)(fb1 + fs1 * (quad * 16));
    c11 = *(const half8*)(fb1 + fs1 * (64 + quad * 16));

    auto step = [&](int sn, const char* Lc, char* Ln,
                    half8& a00, half8& a01, half8& a10, half8& a11,
                    half8& b00, half8& b01, half8& b10, half8& b11) {
        #pragma unroll
        for (int t = 0; t < 4; ++t)
            glds16(gB + (size_t)(2 * sn + kiw) * 8192 + cof[t], Ln + kiw * 8192 + cof[t]);
        b00 = *(const half8*)(fb0 + fs0 * (sn * 128 + quad * 16));
        b01 = *(const half8*)(fb0 + fs0 * (sn * 128 + 64 + quad * 16));
        b10 = *(const half8*)(fb1 + fs1 * (sn * 128 + quad * 16));
        b11 = *(const half8*)(fb1 + fs1 * (sn * 128 + 64 + quad * 16));
        asm volatile("s_waitcnt vmcnt(8)" ::: "memory");
        __builtin_amdgcn_s_barrier();
        __builtin_amdgcn_sched_barrier(0);
        #pragma unroll
        for (int ki = 0; ki < 2; ++ki) {
            const half8 a0 = ki ? a01 : a00;
            const half8 a1 = ki ? a11 : a10;
            #pragma unroll
            for (int j = 0; j < 4; ++j) {
                half8 b = *(const half8*)(Lc + ki * 8192 + brd + j * 256);
                acc[0][j] = __builtin_amdgcn_mfma_f32_16x16x32_f16(a0, b, acc[0][j], 0, 0, 0);
                acc[1][j] = __builtin_amdgcn_mfma_f32_16x16x32_f16(a1, b, acc[1][j], 0, 0, 0);
            }
        }
        __builtin_amdgcn_sched_barrier(0);
        __builtin_amdgcn_s_barrier();
    };

    for (int h = 0; h < 8; ++h) {
        const int s1 = 2 * h + 1;
        step(s1, L, L + 16384, c00, c01, c10, c11, n00, n01, n10, n11);
        step((s1 < 15) ? s1 + 1 : 0, L + 16384, L, n00, n01, n10, n11, c00, c01, c10, c11);
    }

    #pragma unroll
    for (int j = 0; j < 4; ++j) {
        const int n = wc * 64 + j * 16 + lm;
        #pragma unroll
        for (int mi = 0; mi < 2; ++mi) {
            const int m0 = mt * 64 + wr * 32 + mi * 16 + quad * 4;
            #pragma unroll
            for (int r = 0; r < 4; ++r)
                y1p[((size_t)tx * 3136 + m0 + r) * 128 + n] = acc[mi][j][r];
        }
    }
}

// ========= y1 reduce (18 slices) + bias + relu, fused with raw_mean =========
__global__ __launch_bounds__(256)
void y1r_rm(const float* __restrict__ y1p, const float* __restrict__ bias,
            float* __restrict__ y1,
            const half_t* __restrict__ rh, float* __restrict__ concat)
{
    if (blockIdx.x < 1568) {
        const int t = blockIdx.x * 256 + threadIdx.x;
        const int n = t & 127;
        float s = bias[n];
        #pragma unroll
        for (int ks = 0; ks < 18; ++ks) s += y1p[(size_t)ks * 3136 * 128 + t];
        y1[t] = fmaxf(s, 0.f);
    } else {
        const int t = (blockIdx.x - 1568) * 256 + threadIdx.x;
        const int n = t & 2047, b = (t >> 11) & 15, pc = t >> 15;
        float s = 0.f;
        const int p0 = pc * 49;
        for (int p = p0; p < p0 + 49; ++p)
            s += (float)rh[(size_t)(b * 196 + p) * 2048 + n];
        atomicAdd(concat + (size_t)b * 10240 + 8192 + n, s * (1.f / 196.f));
    }
}

// ================= tidy helper (wave per output) =================
__device__ __forceinline__ void tidy_one(const float* in, const float* wr, float bi,
                                         float* dst, int lane)
{
    float acc = in[lane] * wr[lane] + in[lane + 64] * wr[lane + 64];
    #pragma unroll
    for (int s = 32; s > 0; s >>= 1) acc += __shfl_down(acc, s, 64);
    if (lane == 0) *dst = acc + bi;
}

// ================= conv_s2 body =================
__device__ __forceinline__ void conv_s2_body(int t, const float* __restrict__ in,
                                             const float* __restrict__ wt,
                                             const float* __restrict__ bias,
                                             float* __restrict__ out, int Win, int Wout)
{
    const int oc = t & 127;
    const int pos = (t >> 7) % (Wout * Wout);
    const int b = t / (128 * Wout * Wout);
    if (b >= 16) return;
    const int oy = pos / Wout, ox = pos % Wout;
    float acc = bias[oc];
    for (int dy = 0; dy < 3; ++dy) {
        const int y = oy * 2 + dy - 1;
        if (y < 0 || y >= Win) continue;
        for (int dx = 0; dx < 3; ++dx) {
            const int x = ox * 2 + dx - 1;
            if (x < 0 || x >= Win) continue;
            const float* ip = in + (size_t)(b * Win * Win + y * Win + x) * 128;
            const float* wp = wt + (size_t)(dy * 3 + dx) * 16384 + oc;
            for (int ic = 0; ic < 128; ++ic)
                acc += ip[ic] * wp[ic * 128];
        }
    }
    out[(size_t)(b * Wout * Wout + pos) * 128 + oc] = fmaxf(acc, 0.f);
}

// ============ fused: conv_s2 y1->y2 (blocks 0..391)  ||  tidy level-1 (392..5095) ============
__global__ __launch_bounds__(256)
void conv2_tidy1(const float* __restrict__ y1, const float* __restrict__ wt2t,
                 const float* __restrict__ b2d, float* __restrict__ y2,
                 const float* __restrict__ w1t, const float* __restrict__ b1t,
                 float* __restrict__ scores)
{
    if (blockIdx.x < 392) {
        conv_s2_body(blockIdx.x * 256 + threadIdx.x, y1, wt2t, b2d, y2, 14, 7);
    } else {
        const int wid = (blockIdx.x - 392) * 4 + (threadIdx.x >> 6);
        const int lane = threadIdx.x & 63;
        if (wid >= 16 * 1176) return;
        const int b = wid / 1176, i1 = wid % 1176;
        const int ch = i1 / 196, pos = i1 % 196;
        tidy_one(y1 + (size_t)(b * 196 + pos) * 128, w1t + ch * 128, b1t[ch],
                 scores + b * 1614 + i1, lane);
    }
}

// ============ fused: conv_s2 y2->y3 (blocks 0..127)  ||  tidy level-2 (128..1303) ============
__global__ __launch_bounds__(256)
void conv3_tidy2(const float* __restrict__ y2, const float* __restrict__ wt3t,
                 const float* __restrict__ b3d, float* __restrict__ y3,
                 const float* __restrict__ w2t, const float* __restrict__ b2t,
                 float* __restrict__ scores)
{
    if (blockIdx.x < 128) {
        conv_s2_body(blockIdx.x * 256 + threadIdx.x, y2, wt3t, b3d, y3, 7, 4);
    } else {
        const int wid = (blockIdx.x - 128) * 4 + (threadIdx.x >> 6);
        const int lane = threadIdx.x & 63;
        if (wid >= 16 * 294) return;
        const int b = wid / 294, i2 = wid % 294;
        const int ch = i2 / 49, pos = i2 % 49;
        tidy_one(y2 + (size_t)(b * 49 + pos) * 128, w2t + ch * 128, b2t[ch],
                 scores + b * 1614 + 1176 + i2, lane);
    }
}

// ================= tidy level-3 =================
__global__ __launch_bounds__(256)
void tidy3(const float* __restrict__ y3, const float* __restrict__ w3t,
           const float* __restrict__ b3t, float* __restrict__ scores)
{
    const int wid = blockIdx.x * 4 + (threadIdx.x >> 6);
    const int lane = threadIdx.x & 63;
    if (wid >= 16 * 144) return;
    const int b = wid / 144, i3 = wid % 144;
    const int ch = i3 / 16, pos = i3 % 16;
    tidy_one(y3 + (size_t)(b * 16 + pos) * 128, w3t + ch * 128, b3t[ch],
             scores + b * 1614 + 1470 + i3, lane);
}

// ================= NMS: register-resident, shuffle reduce =================
__global__ __launch_bounds__(256)
void nms(const float* __restrict__ scores, const int* __restrict__ anchors,
         int* __restrict__ top_idx)
{
    __shared__ float wv_v[4];
    __shared__ int wv_i[4];
    __shared__ int s_pick;
    const int b = blockIdx.x, tid = threadIdx.x;
    const int lane = tid & 63, wv = tid >> 6;
    float sc[7], ay0[7], ax0[7], ay1[7], ax1[7];
    unsigned int vmask = 0;
    #pragma unroll
    for (int j = 0; j < 7; ++j) {
        const int i = tid + j * 256;
        if (i < 1614) {
            sc[j]  = scores[b * 1614 + i];
            ay0[j] = (float)anchors[i * 4 + 0];
            ax0[j] = (float)anchors[i * 4 + 1];
            ay1[j] = (float)anchors[i * 4 + 2];
            ax1[j] = (float)anchors[i * 4 + 3];
            vmask |= 1u << j;
        }
    }
    for (int r = 0; r < 4; ++r) {
        float bv = -INFINITY; int bi = 0x7fffffff;
        #pragma unroll
        for (int j = 0; j < 7; ++j) {
            if (vmask & (1u << j)) {
                const float v = sc[j];
                const int i = tid + j * 256;
                if (v > bv || (v == bv && i < bi)) { bv = v; bi = i; }
            }
        }
        #pragma unroll
        for (int s = 32; s > 0; s >>= 1) {
            const float v2 = __shfl_down(bv, s, 64);
            const int   i2 = __shfl_down(bi, s, 64);
            if (v2 > bv || (v2 == bv && i2 < bi)) { bv = v2; bi = i2; }
        }
        if (lane == 0) { wv_v[wv] = bv; wv_i[wv] = bi; }
        __syncthreads();
        if (tid == 0) {
            float fv = wv_v[0]; int fi = wv_i[0];
            #pragma unroll
            for (int k = 1; k < 4; ++k)
                if (wv_v[k] > fv || (wv_v[k] == fv && wv_i[k] < fi)) { fv = wv_v[k]; fi = wv_i[k]; }
            s_pick = fi;
            top_idx[b * 4 + r] = fi;
        }
        __syncthreads();
        const int pick = s_pick;
        const float py0 = (float)anchors[pick * 4 + 0], px0 = (float)anchors[pick * 4 + 1];
        const float py1 = (float)anchors[pick * 4 + 2], px1 = (float)anchors[pick * 4 + 3];
        const float pa = (py1 - py0) * (px1 - px0);
        #pragma unroll
        for (int j = 0; j < 7; ++j) {
            if (vmask & (1u << j)) {
                const float ih = fminf(ay1[j], py1) - fmaxf(ay0[j], py0);
                const float iw = fminf(ax1[j], px1) - fmaxf(ax0[j], px0);
                const float inter = (ih < 0.f || iw < 0.f) ? 0.f : ih * iw;
                const float area = (ay1[j] - ay0[j]) * (ax1[j] - ax0[j]);
                const float iou = inter / ((area + pa) - inter);
                if (iou >= 0.25f) vmask &= ~(1u << j);
            }
        }
    }
}

// ================= crop_mean =================
__global__ __launch_bounds__(256)
void crop_mean(const float* __restrict__ x, const int* __restrict__ anchors,
               const int* __restrict__ top_idx, float* __restrict__ abar)
{
    __shared__ float red[256];
    const int bi = blockIdx.x;               // 6144
    const int q = bi / 96, rem = bi % 96, c = rem >> 5, r = rem & 31;
    const int tid = threadIdx.x;
    const int cc = tid & 31, ps = tid >> 5;
    const int idx = top_idx[q];
    const int y0 = anchors[idx * 4 + 0], x0 = anchors[idx * 4 + 1];
    const int y1 = anchors[idx * 4 + 2], x1 = anchors[idx * 4 + 3];
    const float hh = (float)(y1 - y0), ww = (float)(x1 - x0);
    const float* xb = x + (size_t)((q >> 2) * 3 + c) * 200704;
    float acc = 0.f;
    for (int p = ps; p < 49; p += 8) {
        const int oy = p / 7, ox = p % 7;
        const int typ = oy * 32 + r;
        const int txp = ox * 32 + cc;
        const float sy = (float)typ * (hh - 1.0f) / 223.0f;
        const float fy = floorf(sy);
        const float wy = sy - fy;
        const int iy0 = y0 + (int)fy;
        const int iy1 = min(iy0 + 1, y1 - 1);
        const float sx = (float)txp * (ww - 1.0f) / 223.0f;
        const float fx = floorf(sx);
        const float wx = sx - fx;
        const int ix0 = x0 + (int)fx;
        const int ix1 = min(ix0 + 1, x1 - 1);
        const int ry0 = iy0 - 224, ry1 = iy1 - 224;
        const int rx0 = ix0 - 224, rx1 = ix1 - 224;
        const bool vy0 = (ry0 >= 0 && ry0 < 448), vy1 = (ry1 >= 0 && ry1 < 448);
        const bool vx0 = (rx0 >= 0 && rx0 < 448), vx1 = (rx1 >= 0 && rx1 < 448);
        const float v00 = (vy0 && vx0) ? xb[(size_t)ry0 * 448 + rx0] : 0.f;
        const float v01 = (vy0 && vx1) ? xb[(size_t)ry0 * 448 + rx1] : 0.f;
        const float v10 = (vy1 && vx0) ? xb[(size_t)ry1 * 448 + rx0] : 0.f;
        const float v11 = (vy1 && vx1) ? xb[(size_t)ry1 * 448 + rx1] : 0.f;
        const float top = v00 * (1.f - wx) + v01 * wx;
        const float bot = v10 * (1.f - wx) + v11 * wx;
        acc += top * (1.f - wy) + bot * wy;
    }
    red[tid] = acc;
    __syncthreads();
    if (tid < 32) {
        float s = 0.f;
        #pragma unroll
        for (int k = 0; k < 8; ++k) s += red[tid + 32 * k];
        abar[(size_t)q * 3072 + c * 1024 + r * 32 + cc] = s * (1.f / 49.f);
    }
}

// ================= part_gemm =================
__global__ __launch_bounds__(256)
void part_gemm(const float* __restrict__ abar, const half_t* __restrict__ Bh,
               float* __restrict__ concat)
{
    __shared__ __align__(16) char L[12288];
    const int tid = threadIdx.x, lane = tid & 63, wv = tid >> 6;
    const int lm = lane & 15, quad = lane >> 4;
    const int nt = blockIdx.x, ks = blockIdx.y;
    const char* gBh = (const char*)Bh + ((size_t)nt * 96 + ks * 12) * 4096 + lane * 16;
    const int am = tid & 63, akg = tid >> 6;

    floatx4 acc[4], accl[4];
    const floatx4 fz = {0.f, 0.f, 0.f, 0.f};
    #pragma unroll
    for (int j = 0; j < 4; ++j) { acc[j] = fz; accl[j] = fz; }

    for (int s = 0; s < 12; ++s) {
        {
            const float* pa = abar + (size_t)am * 3072 + (ks * 12 + s) * 32 + akg * 8;
            float f[8];
            *(float4*)&f[0] = *(const float4*)pa;
            *(float4*)&f[4] = *(const float4*)(pa + 4);
            half8 h, l;
            #pragma unroll
            for (int j = 0; j < 8; ++j) {
                const half_t hh = (half_t)f[j];
                h[j] = hh;
                l[j] = (half_t)(f[j] - (float)hh);
            }
            *(half8*)(L + (akg * 64 + am) * 16) = h;
            *(half8*)(L + 4096 + (akg * 64 + am) * 16) = l;
        }
        glds16(gBh + (size_t)s * 4096 + wv * 1024, L + 8192 + wv * 1024);
        __syncthreads();
        half8 ah, al, bh[4];
        ah = *(const half8*)(L + (quad * 64 + wv * 16 + lm) * 16);
        al = *(const half8*)(L + 4096 + (quad * 64 + wv * 16 + lm) * 16);
        #pragma unroll
        for (int j = 0; j < 4; ++j) bh[j] = *(const half8*)(L + 8192 + (quad * 64 + j * 16 + lm) * 16);
        #pragma unroll
        for (int j = 0; j < 4; ++j) {
            acc[j]  = __builtin_amdgcn_mfma_f32_16x16x32_f16(ah, bh[j], acc[j], 0, 0, 0);
            accl[j] = __builtin_amdgcn_mfma_f32_16x16x32_f16(al, bh[j], accl[j], 0, 0, 0);
        }
        __syncthreads();
    }
    #pragma unroll
    for (int j = 0; j < 4; ++j) {
        const int n = nt * 64 + j * 16 + lm;
        #pragma unroll
        for (int r = 0; r < 4; ++r) {
            const int m = wv * 16 + quad * 4 + r;
            atomicAdd(concat + (size_t)(m >> 2) * 10240 + (m & 3) * 2048 + n,
                      acc[j][r] + accl[j][r]);
        }
    }
}

// ================= classifier GEMM =================
__global__ __launch_bounds__(256)
void cls_gemm(const float* __restrict__ concat, const float* __restrict__ w,
              float* __restrict__ out)
{
    __shared__ float ws_[8 * 321];
    __shared__ float cs_[16 * 321];
    __shared__ float red[256];
    const int nchunk = blockIdx.x, ks = blockIdx.y;
    const int tid = threadIdx.x;
    for (int i = tid; i < 2560; i += 256) {
        const int r = i / 320, k = i % 320;
        ws_[r * 321 + k] = w[(size_t)(nchunk * 8 + r) * 10240 + ks * 320 + k];
    }
    for (int i = tid; i < 5120; i += 256) {
        const int r = i / 320, k = i % 320;
        cs_[r * 321 + k] = concat[(size_t)r * 10240 + ks * 320 + k];
    }
    __syncthreads();
    const int b = tid & 15, c = (tid >> 4) & 7, hf = tid >> 7;
    const float* cp = cs_ + b * 321 + hf * 160;
    const float* wp = ws_ + c * 321 + hf * 160;
    float a = 0.f;
    #pragma unroll 8
    for (int k = 0; k < 160; ++k) a += cp[k] * wp[k];
    red[tid] = a;
    __syncthreads();
    if (tid < 128) atomicAdd(out + b * 200 + nchunk * 8 + c, red[tid] + red[tid + 128]);
}

extern "C" void kernel_launch(void* const* d_in, const int* in_sizes, int n_in,
                              void* d_out, int out_size, void* d_ws, size_t ws_size,
                              hipStream_t stream)
{
    const float* x     = (const float*)d_in[0];
    const float* bb_w  = (const float*)d_in[1];
    const float* bb_b  = (const float*)d_in[2];
    const float* n1_dw = (const float*)d_in[3];
    const float* n1_db = (const float*)d_in[4];
    const float* n1_tw = (const float*)d_in[5];
    const float* n1_tb = (const float*)d_in[6];
    const float* n2_dw = (const float*)d_in[7];
    const float* n2_db = (const float*)d_in[8];
    const float* n2_tw = (const float*)d_in[9];
    const float* n2_tb = (const float*)d_in[10];
    const float* n3_dw = (const float*)d_in[11];
    const float* n3_db = (const float*)d_in[12];
    const float* n3_tw = (const float*)d_in[13];
    const float* n3_tb = (const float*)d_in[14];
    const float* cn_w  = (const float*)d_in[15];
    const float* cn_b  = (const float*)d_in[16];
    const int*   anchors = (const int*)d_in[17];
    float* out = (float*)d_out;
    char* W = (char*)d_ws;

    half_t* bbwh  = (half_t*)(W + 0);
    float*  zpad  = (float*)(W + 12582912);
    int*    topidx= (int*)(W + 12583936);
    float*  scores= (float*)(W + 12584960);
    float*  y1    = (float*)(W + 12688384);
    float*  y2    = (float*)(W + 14294016);
    float*  y3    = (float*)(W + 14695424);
    float*  concat= (float*)(W + 14826496);
    half_t* w1h   = (half_t*)(W + 15481856);
    float*  wt2t  = (float*)(W + 20200448);
    float*  wt3t  = (float*)(W + 20790272);
    char* E = W + 21380096;
    half_t* xh    = (half_t*)E;
    float*  y1p   = (float*)E;      // alias: xh dead after gemm_x
    char* F = W + 60701696;
    half_t* rawh  = (half_t*)F;
    float*  abar  = (float*)F;      // alias: raw dead after gemm_nav + y1r_rm

    prep_all<<<3902, 256, 0, stream>>>(x, bb_w, n1_dw, n2_dw, n3_dw, cn_b, bb_b,
                                       xh, bbwh, w1h, wt2t, wt3t, out, zpad, concat);

    gemm_x<<<dim3(16, 49), 256, 0, stream>>>(xh, bbwh, bb_b, rawh);
    gemm_nav<<<dim3(18, 49), 256, 0, stream>>>(rawh, w1h, (const char*)zpad, y1p);
    y1r_rm<<<2080, 256, 0, stream>>>(y1p, n1_db, y1, rawh, concat);

    conv2_tidy1<<<5096, 256, 0, stream>>>(y1, wt2t, n2_db, y2, n1_tw, n1_tb, scores);
    conv3_tidy2<<<1304, 256, 0, stream>>>(y2, wt3t, n3_db, y3, n2_tw, n2_tb, scores);
    tidy3<<<576, 256, 0, stream>>>(y3, n3_tw, n3_tb, scores);

    nms<<<16, 256, 0, stream>>>(scores, anchors, topidx);
    crop_mean<<<6144, 256, 0, stream>>>(x, anchors, topidx, abar);

    part_gemm<<<dim3(32, 8), 256, 0, stream>>>(abar, bbwh, concat);
    cls_gemm<<<dim3(25, 32), 256, 0, stream>>>(concat, cn_w, out);
}

// Round 8
// 373.416 us; speedup vs baseline: 1.0650x; 1.0650x over previous
//
#include <hip/hip_runtime.h>
#include <cstdint>
#include <math.h>

typedef _Float16 half_t;
typedef __attribute__((ext_vector_type(8))) _Float16 half8;
typedef __attribute__((ext_vector_type(4))) float floatx4;

// ---------------- workspace byte layout ----------------
// bbwh   @ 0            12,582,912   fp16 [32 nt][96 s][4 kg][64 n][16B]
// zpad   @ 12,582,912   1,024
// topidx @ 12,583,936   1,024
// scores @ 12,584,960   103,424
// y1     @ 12,688,384   1,605,632
// y2     @ 14,294,016   401,408
// y3     @ 14,695,424   131,072
// concat @ 14,826,496   655,360
// w1h    @ 15,481,856   4,718,592    fp16 [9 tap][64 s][4 kg][128 n][16B]
// wt2t   @ 20,200,448   589,824
// wt3t   @ 20,790,272   589,824
// E      @ 21,380,096   39,321,600:  phase1 xh / phase2 y1p
// F      @ 60,701,696:  phase1 rawh fp16 / phase2 abar fp32
// end 86,391,808

typedef __attribute__((address_space(3))) unsigned int lds_u32;
typedef const __attribute__((address_space(1))) unsigned int glb_u32;
__device__ __forceinline__ void glds16(const void* g, void* l) {
    __builtin_amdgcn_global_load_lds((glb_u32*)g, (lds_u32*)l, 16, 0, 0);
}

// ================= prep_all =================
__global__ __launch_bounds__(256)
void prep_all(const float* __restrict__ x, const float* __restrict__ bbw,
              const float* __restrict__ n1dw, const float* __restrict__ n2dw,
              const float* __restrict__ n3dw, const float* __restrict__ cnb,
              const float* __restrict__ bbb,
              half_t* __restrict__ xh,
              half_t* __restrict__ bh, half_t* __restrict__ w1h,
              float* __restrict__ wt2t, float* __restrict__ wt3t,
              float* __restrict__ out, float* __restrict__ zpad,
              float* __restrict__ concat)
{
    const int t = blockIdx.x * 256 + threadIdx.x;
    if (t < 307200) {
        const int m = t % 3200, s = t / 3200;
        const int mt = m >> 7, mr = m & 127;
        float f[32];
        if (m < 3136) {
            const int bq = m / 196, pos = m % 196, oy = pos / 14, ox = pos % 14;
            const int c = s >> 5, r = s & 31;
            const float* p = x + ((size_t)(bq * 3 + c) * 448 + oy * 32 + r) * 448 + ox * 32;
            #pragma unroll
            for (int i = 0; i < 8; ++i) *(float4*)&f[i * 4] = *(const float4*)(p + i * 4);
        } else {
            #pragma unroll
            for (int j = 0; j < 32; ++j) f[j] = 0.f;
        }
        #pragma unroll
        for (int kg = 0; kg < 4; ++kg) {
            half8 h;
            #pragma unroll
            for (int j = 0; j < 8; ++j) h[j] = (half_t)f[kg * 8 + j];
            const size_t dst = (((size_t)(mt * 96 + s) * 4 + kg) * 128 + mr) * 8;
            *(half8*)(xh + dst) = h;
        }
    } else if (t < 503808) {
        const int t2 = t - 307200;
        const int n = t2 & 2047, s = t2 >> 11;
        const float* p = bbw + (size_t)n * 3072 + s * 32;
        float f[32];
        #pragma unroll
        for (int i = 0; i < 8; ++i) *(float4*)&f[i * 4] = *(const float4*)(p + i * 4);
        const int nt = n >> 6, nr = n & 63;
        #pragma unroll
        for (int kg = 0; kg < 4; ++kg) {
            half8 h;
            #pragma unroll
            for (int j = 0; j < 8; ++j) h[j] = (half_t)f[kg * 8 + j];
            const size_t dst = (((size_t)(nt * 96 + s) * 4 + kg) * 64 + nr) * 8;
            *(half8*)(bh + dst) = h;
        }
    } else if (t < 536576) {
        const int t2 = t - 503808;
        const int n = t2 >> 8, ic8 = t2 & 255;
        const int s = ic8 >> 2, kg = ic8 & 3;
        const float* src = n1dw + ((size_t)n * 2048 + ic8 * 8) * 9;
        float buf[72];
        #pragma unroll
        for (int i = 0; i < 18; ++i) *(float4*)&buf[i * 4] = *(const float4*)(src + i * 4);
        #pragma unroll
        for (int tap = 0; tap < 9; ++tap) {
            half8 h;
            #pragma unroll
            for (int j = 0; j < 8; ++j) h[j] = (half_t)buf[j * 9 + tap];
            const size_t dst = (((size_t)(tap * 64 + s) * 4 + kg) * 128 + n) * 8;
            *(half8*)(w1h + dst) = h;
        }
    } else if (t < 684032) {
        const int t2 = t - 536576;
        const int oc = t2 % 128, rest = t2 / 128, ic = rest % 128, tap = rest / 128;
        wt2t[(tap * 128 + ic) * 128 + oc] = n2dw[((size_t)oc * 128 + ic) * 9 + tap];
    } else if (t < 831488) {
        const int t2 = t - 684032;
        const int oc = t2 % 128, rest = t2 / 128, ic = rest % 128, tap = rest / 128;
        wt3t[(tap * 128 + ic) * 128 + oc] = n3dw[((size_t)oc * 128 + ic) * 9 + tap];
    } else if (t < 834688) {
        const int i = t - 831488;
        out[i] = cnb[i % 200];
    } else if (t < 834944) {
        zpad[t - 834688] = 0.f;
    } else if (t < 998784) {
        const int i = t - 834944;
        const int r = i % 10240;
        concat[i] = (r < 8192) ? bbb[r & 2047] : 0.f;
    }
}

// ====== gemm_x: fp16 128Mx128N block, 2 waves (each 64Mx128N), BK=64 ======
// A direct-to-register (8 loads/wave/step), B staged once per block into
// double-buffered LDS; each B ds_read feeds 4 MFMAs (0.25 reads/MFMA).
// Counted vmcnt(16), raw barriers, sched_barrier fences.
__global__ __launch_bounds__(128)
void gemm_x(const half_t* __restrict__ Ah, const half_t* __restrict__ Bh,
            const float* __restrict__ bias, half_t* __restrict__ outh)
{
    __shared__ __align__(16) char L[32768]; // 2 x 16KB B: [ki2][p2][kg4][64n][16B]
    const int tid = threadIdx.x, lane = tid & 63, wv = tid >> 6; // 2 waves
    const int nt = blockIdx.x, mt = blockIdx.y;   // 16 x 25
    const int lm = lane & 15, quad = lane >> 4;

    // A per-lane: frag(mi,ki,st) = pA + (2*st+ki)*8192 + mi*256
    const char* pA = (const char*)Ah + (size_t)mt * 786432
                   + quad * 2048 + (wv * 64 + lm) * 16;
    const char* gB = (const char*)Bh + (size_t)(2 * nt) * 393216 + lane * 16;

    floatx4 acc[4][8];
    const floatx4 fz = {0.f, 0.f, 0.f, 0.f};
    #pragma unroll
    for (int mi = 0; mi < 4; ++mi)
        #pragma unroll
        for (int j = 0; j < 8; ++j) acc[mi][j] = fz;

    half8 aC[8], aN[8];   // index = mi*2 + ki

    // prologue: stage B(0) -> buf0 (8 glds/wave) + load A(0) (8) = 16 outstanding
    #pragma unroll
    for (int i = 0; i < 8; ++i)
        glds16(gB + (size_t)(i >> 2) * 393216 + (size_t)wv * 4096 + (i & 3) * 1024,
               L + wv * 8192 + i * 1024);
    #pragma unroll
    for (int mi = 0; mi < 4; ++mi) {
        aC[mi * 2 + 0] = *(const half8*)(pA + mi * 256);
        aC[mi * 2 + 1] = *(const half8*)(pA + 8192 + mi * 256);
    }

    auto step = [&](int sn, const char* Lc, char* Ln, half8 (&ac)[8], half8 (&an)[8]) {
        #pragma unroll
        for (int i = 0; i < 8; ++i)
            glds16(gB + (size_t)(i >> 2) * 393216 + (size_t)(2 * sn + wv) * 4096 + (i & 3) * 1024,
                   Ln + wv * 8192 + i * 1024);
        const char* pAs = pA + (size_t)sn * 16384;
        #pragma unroll
        for (int mi = 0; mi < 4; ++mi) {
            an[mi * 2 + 0] = *(const half8*)(pAs + mi * 256);
            an[mi * 2 + 1] = *(const half8*)(pAs + 8192 + mi * 256);
        }
        asm volatile("s_waitcnt vmcnt(16)" ::: "memory");
        __builtin_amdgcn_s_barrier();
        __builtin_amdgcn_sched_barrier(0);
        #pragma unroll
        for (int ki = 0; ki < 2; ++ki) {
            #pragma unroll
            for (int j = 0; j < 8; ++j) {
                half8 b = *(const half8*)(Lc + ki * 8192 + (j >> 2) * 4096 + quad * 1024 + ((j & 3) * 16 + lm) * 16);
                #pragma unroll
                for (int mi = 0; mi < 4; ++mi)
                    acc[mi][j] = __builtin_amdgcn_mfma_f32_16x16x32_f16(ac[mi * 2 + ki], b, acc[mi][j], 0, 0, 0);
            }
        }
        __builtin_amdgcn_sched_barrier(0);
        __builtin_amdgcn_s_barrier();
    };

    for (int h = 0; h < 24; ++h) {
        const int s1 = 2 * h + 1;
        step(s1, L, L + 16384, aC, aN);
        step((s1 < 47) ? s1 + 1 : 0, L + 16384, L, aN, aC);
    }

    if (mt == 24 && wv == 1) return;  // rows >= 3136 are zero-pad
    #pragma unroll
    for (int j = 0; j < 8; ++j) {
        const int n = nt * 128 + j * 16 + lm;
        const float bv = bias[n];
        #pragma unroll
        for (int mi = 0; mi < 4; ++mi) {
            const int m0 = mt * 128 + wv * 64 + mi * 16 + quad * 4;
            #pragma unroll
            for (int r = 0; r < 4; ++r)
                outh[(size_t)(m0 + r) * 2048 + n] = (half_t)(acc[mi][j][r] + bv);
        }
    }
}

// ====== gemm_nav: 2 waves (each 64Mx128N), BK=64, grid (18 tx, 25 mtB) ======
__global__ __launch_bounds__(128)
void gemm_nav(const half_t* __restrict__ rawh, const half_t* __restrict__ Bh,
              const char* __restrict__ zpad, float* __restrict__ y1p)
{
    __shared__ __align__(16) char L[32768]; // 2 x 16KB B: [ki2][kg4][128n][16B]
    const int tid = threadIdx.x, lane = tid & 63, wv = tid >> 6; // 2 waves
    const int tx = blockIdx.x;
    const int tap = tx >> 1, ks = tx & 1;
    const int mtB = blockIdx.y;   // 25
    const int lm = lane & 15, quad = lane >> 4;
    const int tile = 2 * mtB + wv;   // 0..49 (49 = pad, masked)

    // per-mi A row pointers (halo/pad -> zpad)
    const char* fb[4]; int fs[4];
    #pragma unroll
    for (int mi = 0; mi < 4; ++mi) {
        const int grow = tile * 64 + mi * 16 + lm;
        const int b = grow / 196, pos = grow % 196, oy = pos / 14, ox = pos % 14;
        const int iy = oy + tap / 3 - 1, ix = ox + tap % 3 - 1;
        const bool av = (grow < 3136) && (iy >= 0 && iy < 14 && ix >= 0 && ix < 14);
        fb[mi] = av ? (const char*)rawh + ((size_t)(b * 196 + iy * 14 + ix)) * 4096 + ks * 2048 : zpad;
        fs[mi] = av ? 1 : 0;
    }

    const char* gB = (const char*)Bh + (size_t)tap * 524288 + (size_t)ks * 262144 + lane * 16;

    floatx4 acc[4][8];
    const floatx4 fz = {0.f, 0.f, 0.f, 0.f};
    #pragma unroll
    for (int mi = 0; mi < 4; ++mi)
        #pragma unroll
        for (int j = 0; j < 8; ++j) acc[mi][j] = fz;

    half8 aC[8], aN[8];

    // prologue: stage B(0) -> buf0 + load A(0) (8+8 = 16 outstanding/wave)
    #pragma unroll
    for (int i = 0; i < 8; ++i)
        glds16(gB + (size_t)wv * 8192 + i * 1024, L + wv * 8192 + i * 1024);
    #pragma unroll
    for (int mi = 0; mi < 4; ++mi) {
        aC[mi * 2 + 0] = *(const half8*)(fb[mi] + fs[mi] * (quad * 16));
        aC[mi * 2 + 1] = *(const half8*)(fb[mi] + fs[mi] * (64 + quad * 16));
    }

    auto step = [&](int sn, const char* Lc, char* Ln, half8 (&ac)[8], half8 (&an)[8]) {
        #pragma unroll
        for (int i = 0; i < 8; ++i)
            glds16(gB + (size_t)(2 * sn + wv) * 8192 + i * 1024, Ln + wv * 8192 + i * 1024);
        #pragma unroll
        for (int mi = 0; mi < 4; ++mi) {
            an[mi * 2 + 0] = *(const half8*)(fb[mi] + fs[mi] * (sn * 128 + quad * 16));
            an[mi * 2 + 1] = *(const half8*)(fb[mi] + fs[mi] * (sn * 128 + 64 + quad * 16));
        }
        asm volatile("s_waitcnt vmcnt(16)" ::: "memory");
        __builtin_amdgcn_s_barrier();
        __builtin_amdgcn_sched_barrier(0);
        #pragma unroll
        for (int ki = 0; ki < 2; ++ki) {
            #pragma unroll
            for (int j = 0; j < 8; ++j) {
                half8 b = *(const half8*)(Lc + ki * 8192 + quad * 2048 + (j * 16 + lm) * 16);
                #pragma unroll
                for (int mi = 0; mi < 4; ++mi)
                    acc[mi][j] = __builtin_amdgcn_mfma_f32_16x16x32_f16(ac[mi * 2 + ki], b, acc[mi][j], 0, 0, 0);
            }
        }
        __builtin_amdgcn_sched_barrier(0);
        __builtin_amdgcn_s_barrier();
    };

    for (int h = 0; h < 8; ++h) {
        const int s1 = 2 * h + 1;
        step(s1, L, L + 16384, aC, aN);
        step((s1 < 15) ? s1 + 1 : 0, L + 16384, L, aN, aC);
    }

    if (tile >= 49) return;
    #pragma unroll
    for (int j = 0; j < 8; ++j) {
        const int n = j * 16 + lm;
        #pragma unroll
        for (int mi = 0; mi < 4; ++mi) {
            const int m0 = tile * 64 + mi * 16 + quad * 4;
            #pragma unroll
            for (int r = 0; r < 4; ++r)
                y1p[((size_t)tx * 3136 + m0 + r) * 128 + n] = acc[mi][j][r];
        }
    }
}

// ========= y1 reduce (18 slices) + bias + relu, fused with raw_mean =========
__global__ __launch_bounds__(256)
void y1r_rm(const float* __restrict__ y1p, const float* __restrict__ bias,
            float* __restrict__ y1,
            const half_t* __restrict__ rh, float* __restrict__ concat)
{
    if (blockIdx.x < 1568) {
        const int t = blockIdx.x * 256 + threadIdx.x;
        const int n = t & 127;
        float s = bias[n];
        #pragma unroll
        for (int ks = 0; ks < 18; ++ks) s += y1p[(size_t)ks * 3136 * 128 + t];
        y1[t] = fmaxf(s, 0.f);
    } else {
        const int t = (blockIdx.x - 1568) * 256 + threadIdx.x;
        const int n = t & 2047, b = (t >> 11) & 15, pc = t >> 15;
        float s = 0.f;
        const int p0 = pc * 49;
        for (int p = p0; p < p0 + 49; ++p)
            s += (float)rh[(size_t)(b * 196 + p) * 2048 + n];
        atomicAdd(concat + (size_t)b * 10240 + 8192 + n, s * (1.f / 196.f));
    }
}

// ================= tidy helper (wave per output) =================
__device__ __forceinline__ void tidy_one(const float* in, const float* wr, float bi,
                                         float* dst, int lane)
{
    float acc = in[lane] * wr[lane] + in[lane + 64] * wr[lane + 64];
    #pragma unroll
    for (int s = 32; s > 0; s >>= 1) acc += __shfl_down(acc, s, 64);
    if (lane == 0) *dst = acc + bi;
}

// ================= conv_s2 body =================
__device__ __forceinline__ void conv_s2_body(int t, const float* __restrict__ in,
                                             const float* __restrict__ wt,
                                             const float* __restrict__ bias,
                                             float* __restrict__ out, int Win, int Wout)
{
    const int oc = t & 127;
    const int pos = (t >> 7) % (Wout * Wout);
    const int b = t / (128 * Wout * Wout);
    if (b >= 16) return;
    const int oy = pos / Wout, ox = pos % Wout;
    float acc = bias[oc];
    for (int dy = 0; dy < 3; ++dy) {
        const int y = oy * 2 + dy - 1;
        if (y < 0 || y >= Win) continue;
        for (int dx = 0; dx < 3; ++dx) {
            const int x = ox * 2 + dx - 1;
            if (x < 0 || x >= Win) continue;
            const float* ip = in + (size_t)(b * Win * Win + y * Win + x) * 128;
            const float* wp = wt + (size_t)(dy * 3 + dx) * 16384 + oc;
            for (int ic = 0; ic < 128; ++ic)
                acc += ip[ic] * wp[ic * 128];
        }
    }
    out[(size_t)(b * Wout * Wout + pos) * 128 + oc] = fmaxf(acc, 0.f);
}

// ============ fused: conv_s2 y1->y2 (blocks 0..391)  ||  tidy level-1 (392..5095) ============
__global__ __launch_bounds__(256)
void conv2_tidy1(const float* __restrict__ y1, const float* __restrict__ wt2t,
                 const float* __restrict__ b2d, float* __restrict__ y2,
                 const float* __restrict__ w1t, const float* __restrict__ b1t,
                 float* __restrict__ scores)
{
    if (blockIdx.x < 392) {
        conv_s2_body(blockIdx.x * 256 + threadIdx.x, y1, wt2t, b2d, y2, 14, 7);
    } else {
        const int wid = (blockIdx.x - 392) * 4 + (threadIdx.x >> 6);
        const int lane = threadIdx.x & 63;
        if (wid >= 16 * 1176) return;
        const int b = wid / 1176, i1 = wid % 1176;
        const int ch = i1 / 196, pos = i1 % 196;
        tidy_one(y1 + (size_t)(b * 196 + pos) * 128, w1t + ch * 128, b1t[ch],
                 scores + b * 1614 + i1, lane);
    }
}

// ============ fused: conv_s2 y2->y3 (blocks 0..127)  ||  tidy level-2 (128..1303) ============
__global__ __launch_bounds__(256)
void conv3_tidy2(const float* __restrict__ y2, const float* __restrict__ wt3t,
                 const float* __restrict__ b3d, float* __restrict__ y3,
                 const float* __restrict__ w2t, const float* __restrict__ b2t,
                 float* __restrict__ scores)
{
    if (blockIdx.x < 128) {
        conv_s2_body(blockIdx.x * 256 + threadIdx.x, y2, wt3t, b3d, y3, 7, 4);
    } else {
        const int wid = (blockIdx.x - 128) * 4 + (threadIdx.x >> 6);
        const int lane = threadIdx.x & 63;
        if (wid >= 16 * 294) return;
        const int b = wid / 294, i2 = wid % 294;
        const int ch = i2 / 49, pos = i2 % 49;
        tidy_one(y2 + (size_t)(b * 49 + pos) * 128, w2t + ch * 128, b2t[ch],
                 scores + b * 1614 + 1176 + i2, lane);
    }
}

// ================= tidy level-3 =================
__global__ __launch_bounds__(256)
void tidy3(const float* __restrict__ y3, const float* __restrict__ w3t,
           const float* __restrict__ b3t, float* __restrict__ scores)
{
    const int wid = blockIdx.x * 4 + (threadIdx.x >> 6);
    const int lane = threadIdx.x & 63;
    if (wid >= 16 * 144) return;
    const int b = wid / 144, i3 = wid % 144;
    const int ch = i3 / 16, pos = i3 % 16;
    tidy_one(y3 + (size_t)(b * 16 + pos) * 128, w3t + ch * 128, b3t[ch],
             scores + b * 1614 + 1470 + i3, lane);
}

// ================= NMS: register-resident, shuffle reduce =================
__global__ __launch_bounds__(256)
void nms(const float* __restrict__ scores, const int* __restrict__ anchors,
         int* __restrict__ top_idx)
{
    __shared__ float wv_v[4];
    __shared__ int wv_i[4];
    __shared__ int s_pick;
    const int b = blockIdx.x, tid = threadIdx.x;
    const int lane = tid & 63, wv = tid >> 6;
    float sc[7], ay0[7], ax0[7], ay1[7], ax1[7];
    unsigned int vmask = 0;
    #pragma unroll
    for (int j = 0; j < 7; ++j) {
        const int i = tid + j * 256;
        if (i < 1614) {
            sc[j]  = scores[b * 1614 + i];
            ay0[j] = (float)anchors[i * 4 + 0];
            ax0[j] = (float)anchors[i * 4 + 1];
            ay1[j] = (float)anchors[i * 4 + 2];
            ax1[j] = (float)anchors[i * 4 + 3];
            vmask |= 1u << j;
        }
    }
    for (int r = 0; r < 4; ++r) {
        float bv = -INFINITY; int bi = 0x7fffffff;
        #pragma unroll
        for (int j = 0; j < 7; ++j) {
            if (vmask & (1u << j)) {
                const float v = sc[j];
                const int i = tid + j * 256;
                if (v > bv || (v == bv && i < bi)) { bv = v; bi = i; }
            }
        }
        #pragma unroll
        for (int s = 32; s > 0; s >>= 1) {
            const float v2 = __shfl_down(bv, s, 64);
            const int   i2 = __shfl_down(bi, s, 64);
            if (v2 > bv || (v2 == bv && i2 < bi)) { bv = v2; bi = i2; }
        }
        if (lane == 0) { wv_v[wv] = bv; wv_i[wv] = bi; }
        __syncthreads();
        if (tid == 0) {
            float fv = wv_v[0]; int fi = wv_i[0];
            #pragma unroll
            for (int k = 1; k < 4; ++k)
                if (wv_v[k] > fv || (wv_v[k] == fv && wv_i[k] < fi)) { fv = wv_v[k]; fi = wv_i[k]; }
            s_pick = fi;
            top_idx[b * 4 + r] = fi;
        }
        __syncthreads();
        const int pick = s_pick;
        const float py0 = (float)anchors[pick * 4 + 0], px0 = (float)anchors[pick * 4 + 1];
        const float py1 = (float)anchors[pick * 4 + 2], px1 = (float)anchors[pick * 4 + 3];
        const float pa = (py1 - py0) * (px1 - px0);
        #pragma unroll
        for (int j = 0; j < 7; ++j) {
            if (vmask & (1u << j)) {
                const float ih = fminf(ay1[j], py1) - fmaxf(ay0[j], py0);
                const float iw = fminf(ax1[j], px1) - fmaxf(ax0[j], px0);
                const float inter = (ih < 0.f || iw < 0.f) ? 0.f : ih * iw;
                const float area = (ay1[j] - ay0[j]) * (ax1[j] - ax0[j]);
                const float iou = inter / ((area + pa) - inter);
                if (iou >= 0.25f) vmask &= ~(1u << j);
            }
        }
    }
}

// ================= crop_mean =================
__global__ __launch_bounds__(256)
void crop_mean(const float* __restrict__ x, const int* __restrict__ anchors,
               const int* __restrict__ top_idx, float* __restrict__ abar)
{
    __shared__ float red[256];
    const int bi = blockIdx.x;               // 6144
    const int q = bi / 96, rem = bi % 96, c = rem >> 5, r = rem & 31;
    const int tid = threadIdx.x;
    const int cc = tid & 31, ps = tid >> 5;
    const int idx = top_idx[q];
    const int y0 = anchors[idx * 4 + 0], x0 = anchors[idx * 4 + 1];
    const int y1 = anchors[idx * 4 + 2], x1 = anchors[idx * 4 + 3];
    const float hh = (float)(y1 - y0), ww = (float)(x1 - x0);
    const float* xb = x + (size_t)((q >> 2) * 3 + c) * 200704;
    float acc = 0.f;
    for (int p = ps; p < 49; p += 8) {
        const int oy = p / 7, ox = p % 7;
        const int typ = oy * 32 + r;
        const int txp = ox * 32 + cc;
        const float sy = (float)typ * (hh - 1.0f) / 223.0f;
        const float fy = floorf(sy);
        const float wy = sy - fy;
        const int iy0 = y0 + (int)fy;
        const int iy1 = min(iy0 + 1, y1 - 1);
        const float sx = (float)txp * (ww - 1.0f) / 223.0f;
        const float fx = floorf(sx);
        const float wx = sx - fx;
        const int ix0 = x0 + (int)fx;
        const int ix1 = min(ix0 + 1, x1 - 1);
        const int ry0 = iy0 - 224, ry1 = iy1 - 224;
        const int rx0 = ix0 - 224, rx1 = ix1 - 224;
        const bool vy0 = (ry0 >= 0 && ry0 < 448), vy1 = (ry1 >= 0 && ry1 < 448);
        const bool vx0 = (rx0 >= 0 && rx0 < 448), vx1 = (rx1 >= 0 && rx1 < 448);
        const float v00 = (vy0 && vx0) ? xb[(size_t)ry0 * 448 + rx0] : 0.f;
        const float v01 = (vy0 && vx1) ? xb[(size_t)ry0 * 448 + rx1] : 0.f;
        const float v10 = (vy1 && vx0) ? xb[(size_t)ry1 * 448 + rx0] : 0.f;
        const float v11 = (vy1 && vx1) ? xb[(size_t)ry1 * 448 + rx1] : 0.f;
        const float top = v00 * (1.f - wx) + v01 * wx;
        const float bot = v10 * (1.f - wx) + v11 * wx;
        acc += top * (1.f - wy) + bot * wy;
    }
    red[tid] = acc;
    __syncthreads();
    if (tid < 32) {
        float s = 0.f;
        #pragma unroll
        for (int k = 0; k < 8; ++k) s += red[tid + 32 * k];
        abar[(size_t)q * 3072 + c * 1024 + r * 32 + cc] = s * (1.f / 49.f);
    }
}

// ================= part_gemm =================
__global__ __launch_bounds__(256)
void part_gemm(const float* __restrict__ abar, const half_t* __restrict__ Bh,
               float* __restrict__ concat)
{
    __shared__ __align__(16) char L[12288];
    const int tid = threadIdx.x, lane = tid & 63, wv = tid >> 6;
    const int lm = lane & 15, quad = lane >> 4;
    const int nt = blockIdx.x, ks = blockIdx.y;
    const char* gBh = (const char*)Bh + ((size_t)nt * 96 + ks * 12) * 4096 + lane * 16;
    const int am = tid & 63, akg = tid >> 6;

    floatx4 acc[4], accl[4];
    const floatx4 fz = {0.f, 0.f, 0.f, 0.f};
    #pragma unroll
    for (int j = 0; j < 4; ++j) { acc[j] = fz; accl[j] = fz; }

    for (int s = 0; s < 12; ++s) {
        {
            const float* pa = abar + (size_t)am * 3072 + (ks * 12 + s) * 32 + akg * 8;
            float f[8];
            *(float4*)&f[0] = *(const float4*)pa;
            *(float4*)&f[4] = *(const float4*)(pa + 4);
            half8 h, l;
            #pragma unroll
            for (int j = 0; j < 8; ++j) {
                const half_t hh = (half_t)f[j];
                h[j] = hh;
                l[j] = (half_t)(f[j] - (float)hh);
            }
            *(half8*)(L + (akg * 64 + am) * 16) = h;
            *(half8*)(L + 4096 + (akg * 64 + am) * 16) = l;
        }
        glds16(gBh + (size_t)s * 4096 + wv * 1024, L + 8192 + wv * 1024);
        __syncthreads();
        half8 ah, al, bh[4];
        ah = *(const half8*)(L + (quad * 64 + wv * 16 + lm) * 16);
        al = *(const half8*)(L + 4096 + (quad * 64 + wv * 16 + lm) * 16);
        #pragma unroll
        for (int j = 0; j < 4; ++j) bh[j] = *(const half8*)(L + 8192 + (quad * 64 + j * 16 + lm) * 16);
        #pragma unroll
        for (int j = 0; j < 4; ++j) {
            acc[j]  = __builtin_amdgcn_mfma_f32_16x16x32_f16(ah, bh[j], acc[j], 0, 0, 0);
            accl[j] = __builtin_amdgcn_mfma_f32_16x16x32_f16(al, bh[j], accl[j], 0, 0, 0);
        }
        __syncthreads();
    }
    #pragma unroll
    for (int j = 0; j < 4; ++j) {
        const int n = nt * 64 + j * 16 + lm;
        #pragma unroll
        for (int r = 0; r < 4; ++r) {
            const int m = wv * 16 + quad * 4 + r;
            atomicAdd(concat + (size_t)(m >> 2) * 10240 + (m & 3) * 2048 + n,
                      acc[j][r] + accl[j][r]);
        }
    }
}

// ================= classifier GEMM =================
__global__ __launch_bounds__(256)
void cls_gemm(const float* __restrict__ concat, const float* __restrict__ w,
              float* __restrict__ out)
{
    __shared__ float ws_[8 * 321];
    __shared__ float cs_[16 * 321];
    __shared__ float red[256];
    const int nchunk = blockIdx.x, ks = blockIdx.y;
    const int tid = threadIdx.x;
    for (int i = tid; i < 2560; i += 256) {
        const int r = i / 320, k = i % 320;
        ws_[r * 321 + k] = w[(size_t)(nchunk * 8 + r) * 10240 + ks * 320 + k];
    }
    for (int i = tid; i < 5120; i += 256) {
        const int r = i / 320, k = i % 320;
        cs_[r * 321 + k] = concat[(size_t)r * 10240 + ks * 320 + k];
    }
    __syncthreads();
    const int b = tid & 15, c = (tid >> 4) & 7, hf = tid >> 7;
    const float* cp = cs_ + b * 321 + hf * 160;
    const float* wp = ws_ + c * 321 + hf * 160;
    float a = 0.f;
    #pragma unroll 8
    for (int k = 0; k < 160; ++k) a += cp[k] * wp[k];
    red[tid] = a;
    __syncthreads();
    if (tid < 128) atomicAdd(out + b * 200 + nchunk * 8 + c, red[tid] + red[tid + 128]);
}

extern "C" void kernel_launch(void* const* d_in, const int* in_sizes, int n_in,
                              void* d_out, int out_size, void* d_ws, size_t ws_size,
                              hipStream_t stream)
{
    const float* x     = (const float*)d_in[0];
    const float* bb_w  = (const float*)d_in[1];
    const float* bb_b  = (const float*)d_in[2];
    const float* n1_dw = (const float*)d_in[3];
    const float* n1_db = (const float*)d_in[4];
    const float* n1_tw = (const float*)d_in[5];
    const float* n1_tb = (const float*)d_in[6];
    const float* n2_dw = (const float*)d_in[7];
    const float* n2_db = (const float*)d_in[8];
    const float* n2_tw = (const float*)d_in[9];
    const float* n2_tb = (const float*)d_in[10];
    const float* n3_dw = (const float*)d_in[11];
    const float* n3_db = (const float*)d_in[12];
    const float* n3_tw = (const float*)d_in[13];
    const float* n3_tb = (const float*)d_in[14];
    const float* cn_w  = (const float*)d_in[15];
    const float* cn_b  = (const float*)d_in[16];
    const int*   anchors = (const int*)d_in[17];
    float* out = (float*)d_out;
    char* W = (char*)d_ws;

    half_t* bbwh  = (half_t*)(W + 0);
    float*  zpad  = (float*)(W + 12582912);
    int*    topidx= (int*)(W + 12583936);
    float*  scores= (float*)(W + 12584960);
    float*  y1    = (float*)(W + 12688384);
    float*  y2    = (float*)(W + 14294016);
    float*  y3    = (float*)(W + 14695424);
    float*  concat= (float*)(W + 14826496);
    half_t* w1h   = (half_t*)(W + 15481856);
    float*  wt2t  = (float*)(W + 20200448);
    float*  wt3t  = (float*)(W + 20790272);
    char* E = W + 21380096;
    half_t* xh    = (half_t*)E;
    float*  y1p   = (float*)E;      // alias: xh dead after gemm_x
    char* F = W + 60701696;
    half_t* rawh  = (half_t*)F;
    float*  abar  = (float*)F;      // alias: raw dead after gemm_nav + y1r_rm

    prep_all<<<3902, 256, 0, stream>>>(x, bb_w, n1_dw, n2_dw, n3_dw, cn_b, bb_b,
                                       xh, bbwh, w1h, wt2t, wt3t, out, zpad, concat);

    gemm_x<<<dim3(16, 25), 128, 0, stream>>>(xh, bbwh, bb_b, rawh);
    gemm_nav<<<dim3(18, 25), 128, 0, stream>>>(rawh, w1h, (const char*)zpad, y1p);
    y1r_rm<<<2080, 256, 0, stream>>>(y1p, n1_db, y1, rawh, concat);

    conv2_tidy1<<<5096, 256, 0, stream>>>(y1, wt2t, n2_db, y2, n1_tw, n1_tb, scores);
    conv3_tidy2<<<1304, 256, 0, stream>>>(y2, wt3t, n3_db, y3, n2_tw, n2_tb, scores);
    tidy3<<<576, 256, 0, stream>>>(y3, n3_tw, n3_tb, scores);

    nms<<<16, 256, 0, stream>>>(scores, anchors, topidx);
    crop_mean<<<6144, 256, 0, stream>>>(x, anchors, topidx, abar);

    part_gemm<<<dim3(32, 8), 256, 0, stream>>>(abar, bbwh, concat);
    cls_gemm<<<dim3(25, 32), 256, 0, stream>>>(concat, cn_w, out);
}

// Round 11
// 369.412 us; speedup vs baseline: 1.0765x; 1.0108x over previous
//
#include <hip/hip_runtime.h>
#include <cstdint>
#include <math.h>

typedef _Float16 half_t;
typedef __attribute__((ext_vector_type(8))) _Float16 half8;
typedef __attribute__((ext_vector_type(4))) float floatx4;

// ---------------- workspace byte layout ----------------
// bbwh   @ 0            12,582,912   fp16 [32 nt][96 s][4 kg][64 n][16B]
// zpad   @ 12,582,912   1,024
// topidx @ 12,583,936   1,024
// scores @ 12,584,960   103,424
// y1     @ 12,688,384   1,605,632
// y2     @ 14,294,016   401,408
// y3     @ 14,695,424   131,072
// concat @ 14,826,496   655,360
// w1h    @ 15,481,856   4,718,592    fp16 [9 tap][64 s][4 kg][128 n][16B]
// wt2t   @ 20,200,448   589,824
// wt3t   @ 20,790,272   589,824
// E      @ 21,380,096   39,321,600:  phase1 xh / phase2 y1p
// F      @ 60,701,696:  phase1 rawh fp16 / phase2 abar fp32
// end 86,391,808

typedef __attribute__((address_space(3))) unsigned int lds_u32;
typedef const __attribute__((address_space(1))) unsigned int glb_u32;
__device__ __forceinline__ void glds16(const void* g, void* l) {
    __builtin_amdgcn_global_load_lds((glb_u32*)g, (lds_u32*)l, 16, 0, 0);
}

// ================= prep_all =================
__global__ __launch_bounds__(256)
void prep_all(const float* __restrict__ x, const float* __restrict__ bbw,
              const float* __restrict__ n1dw, const float* __restrict__ n2dw,
              const float* __restrict__ n3dw, const float* __restrict__ cnb,
              const float* __restrict__ bbb,
              half_t* __restrict__ xh,
              half_t* __restrict__ bh, half_t* __restrict__ w1h,
              float* __restrict__ wt2t, float* __restrict__ wt3t,
              float* __restrict__ out, float* __restrict__ zpad,
              float* __restrict__ concat)
{
    const int t = blockIdx.x * 256 + threadIdx.x;
    if (t < 307200) {
        const int m = t % 3200, s = t / 3200;
        const int mt = m >> 7, mr = m & 127;
        float f[32];
        if (m < 3136) {
            const int bq = m / 196, pos = m % 196, oy = pos / 14, ox = pos % 14;
            const int c = s >> 5, r = s & 31;
            const float* p = x + ((size_t)(bq * 3 + c) * 448 + oy * 32 + r) * 448 + ox * 32;
            #pragma unroll
            for (int i = 0; i < 8; ++i) *(float4*)&f[i * 4] = *(const float4*)(p + i * 4);
        } else {
            #pragma unroll
            for (int j = 0; j < 32; ++j) f[j] = 0.f;
        }
        #pragma unroll
        for (int kg = 0; kg < 4; ++kg) {
            half8 h;
            #pragma unroll
            for (int j = 0; j < 8; ++j) h[j] = (half_t)f[kg * 8 + j];
            const size_t dst = (((size_t)(mt * 96 + s) * 4 + kg) * 128 + mr) * 8;
            *(half8*)(xh + dst) = h;
        }
    } else if (t < 503808) {
        const int t2 = t - 307200;
        const int n = t2 & 2047, s = t2 >> 11;
        const float* p = bbw + (size_t)n * 3072 + s * 32;
        float f[32];
        #pragma unroll
        for (int i = 0; i < 8; ++i) *(float4*)&f[i * 4] = *(const float4*)(p + i * 4);
        const int nt = n >> 6, nr = n & 63;
        #pragma unroll
        for (int kg = 0; kg < 4; ++kg) {
            half8 h;
            #pragma unroll
            for (int j = 0; j < 8; ++j) h[j] = (half_t)f[kg * 8 + j];
            const size_t dst = (((size_t)(nt * 96 + s) * 4 + kg) * 64 + nr) * 8;
            *(half8*)(bh + dst) = h;
        }
    } else if (t < 536576) {
        const int t2 = t - 503808;
        const int n = t2 >> 8, ic8 = t2 & 255;
        const int s = ic8 >> 2, kg = ic8 & 3;
        const float* src = n1dw + ((size_t)n * 2048 + ic8 * 8) * 9;
        float buf[72];
        #pragma unroll
        for (int i = 0; i < 18; ++i) *(float4*)&buf[i * 4] = *(const float4*)(src + i * 4);
        #pragma unroll
        for (int tap = 0; tap < 9; ++tap) {
            half8 h;
            #pragma unroll
            for (int j = 0; j < 8; ++j) h[j] = (half_t)buf[j * 9 + tap];
            const size_t dst = (((size_t)(tap * 64 + s) * 4 + kg) * 128 + n) * 8;
            *(half8*)(w1h + dst) = h;
        }
    } else if (t < 684032) {
        const int t2 = t - 536576;
        const int oc = t2 % 128, rest = t2 / 128, ic = rest % 128, tap = rest / 128;
        wt2t[(tap * 128 + ic) * 128 + oc] = n2dw[((size_t)oc * 128 + ic) * 9 + tap];
    } else if (t < 831488) {
        const int t2 = t - 684032;
        const int oc = t2 % 128, rest = t2 / 128, ic = rest % 128, tap = rest / 128;
        wt3t[(tap * 128 + ic) * 128 + oc] = n3dw[((size_t)oc * 128 + ic) * 9 + tap];
    } else if (t < 834688) {
        const int i = t - 831488;
        out[i] = cnb[i % 200];
    } else if (t < 834944) {
        zpad[t - 834688] = 0.f;
    } else if (t < 998784) {
        const int i = t - 834944;
        const int r = i % 10240;
        concat[i] = (r < 8192) ? bbb[r & 2047] : 0.f;
    }
}

// ====== gemm_x: fp16 64Mx128N, BK=64, 2-wave blocks (each wave 32Mx128N) ======
// [verbatim round-6 best: 57.8 us] A direct-to-register (4 loads/wave/step),
// B double-buffered LDS: each B frag read feeds 2 MFMAs. Counted vmcnt(12).
__global__ __launch_bounds__(128)
void gemm_x(const half_t* __restrict__ Ah, const half_t* __restrict__ Bh,
            const float* __restrict__ bias, half_t* __restrict__ outh)
{
    __shared__ __align__(16) char L[32768]; // 2 x 16KB: [s 2][nh 2][kg 4][64n][16B]
    const int tid = threadIdx.x, lane = tid & 63, wv = tid >> 6; // wv in {0,1}
    const int nt = blockIdx.x, mt = blockIdx.y;   // 16 x 49
    const int lm = lane & 15, quad = lane >> 4;

    // per-lane A pointer: frag(mi,ki,step) = pA + (2*step+ki)*8192 + mi*256
    const char* pA = (const char*)Ah + (size_t)(mt >> 1) * 786432
                   + quad * 2048 + ((mt & 1) * 64 + wv * 32 + lm) * 16;
    const char* gB = (const char*)Bh + (size_t)(2 * nt) * 393216 + lane * 16;

    floatx4 acc[2][8];
    const floatx4 fz = {0.f, 0.f, 0.f, 0.f};
    #pragma unroll
    for (int mi = 0; mi < 2; ++mi)
        #pragma unroll
        for (int j = 0; j < 8; ++j) acc[mi][j] = fz;

    half8 c0, c1, c2, c3, n0, n1, n2, n3; // [mi][ki]: c0=m0k0 c1=m0k1 c2=m1k0 c3=m1k1

    // prologue: stage B(0) -> buf0 (8 glds16/wave), load A(0) (4 loads) = 12 outstanding
    #pragma unroll
    for (int i = 0; i < 8; ++i)
        glds16(gB + (size_t)(i >> 2) * 393216 + (size_t)wv * 4096 + (i & 3) * 1024,
               L + wv * 8192 + i * 1024);
    c0 = *(const half8*)(pA);
    c1 = *(const half8*)(pA + 8192);
    c2 = *(const half8*)(pA + 256);
    c3 = *(const half8*)(pA + 8192 + 256);

    auto step = [&](int sn, const char* Lc, char* Ln,
                    half8& a00, half8& a01, half8& a10, half8& a11,
                    half8& b00, half8& b01, half8& b10, half8& b11) {
        #pragma unroll
        for (int i = 0; i < 8; ++i)
            glds16(gB + (size_t)(i >> 2) * 393216 + (size_t)(2 * sn + wv) * 4096 + (i & 3) * 1024,
                   Ln + wv * 8192 + i * 1024);
        const char* pAs = pA + (size_t)(2 * sn) * 8192;
        b00 = *(const half8*)(pAs);
        b01 = *(const half8*)(pAs + 8192);
        b10 = *(const half8*)(pAs + 256);
        b11 = *(const half8*)(pAs + 8192 + 256);
        asm volatile("s_waitcnt vmcnt(12)" ::: "memory");
        __builtin_amdgcn_s_barrier();
        __builtin_amdgcn_sched_barrier(0);
        #pragma unroll
        for (int ki = 0; ki < 2; ++ki) {
            const half8 a0 = ki ? a01 : a00;
            const half8 a1 = ki ? a11 : a10;
            #pragma unroll
            for (int j = 0; j < 8; ++j) {
                half8 b = *(const half8*)(Lc + ki * 8192 + (j >> 2) * 4096 + quad * 1024 + ((j & 3) * 16 + lm) * 16);
                acc[0][j] = __builtin_amdgcn_mfma_f32_16x16x32_f16(a0, b, acc[0][j], 0, 0, 0);
                acc[1][j] = __builtin_amdgcn_mfma_f32_16x16x32_f16(a1, b, acc[1][j], 0, 0, 0);
            }
        }
        __builtin_amdgcn_sched_barrier(0);
        __builtin_amdgcn_s_barrier();
    };

    for (int h = 0; h < 24; ++h) {
        const int s1 = 2 * h + 1;
        step(s1, L, L + 16384, c0, c1, c2, c3, n0, n1, n2, n3);
        step((s1 < 47) ? s1 + 1 : 0, L + 16384, L, n0, n1, n2, n3, c0, c1, c2, c3);
    }

    #pragma unroll
    for (int j = 0; j < 8; ++j) {
        const int n = nt * 128 + j * 16 + lm;
        const float bv = bias[n];
        #pragma unroll
        for (int mi = 0; mi < 2; ++mi) {
            const int m0 = mt * 64 + wv * 32 + mi * 16 + quad * 4;
            #pragma unroll
            for (int r = 0; r < 4; ++r)
                outh[(size_t)(m0 + r) * 2048 + n] = (half_t)(acc[mi][j][r] + bv);
        }
    }
}

// ====== gemm_nav: 2 waves (each 64Mx128N), BK=64, grid (18 tx, 25 mtB) ======
// [verbatim round-8: fastest measured nav] Counted vmcnt(16).
__global__ __launch_bounds__(128)
void gemm_nav(const half_t* __restrict__ rawh, const half_t* __restrict__ Bh,
              const char* __restrict__ zpad, float* __restrict__ y1p)
{
    __shared__ __align__(16) char L[32768]; // 2 x 16KB B: [ki2][kg4][128n][16B]
    const int tid = threadIdx.x, lane = tid & 63, wv = tid >> 6; // 2 waves
    const int tx = blockIdx.x;
    const int tap = tx >> 1, ks = tx & 1;
    const int mtB = blockIdx.y;   // 25
    const int lm = lane & 15, quad = lane >> 4;
    const int tile = 2 * mtB + wv;   // 0..49 (49 = pad, masked)

    // per-mi A row pointers (halo/pad -> zpad)
    const char* fb[4]; int fs[4];
    #pragma unroll
    for (int mi = 0; mi < 4; ++mi) {
        const int grow = tile * 64 + mi * 16 + lm;
        const int b = grow / 196, pos = grow % 196, oy = pos / 14, ox = pos % 14;
        const int iy = oy + tap / 3 - 1, ix = ox + tap % 3 - 1;
        const bool av = (grow < 3136) && (iy >= 0 && iy < 14 && ix >= 0 && ix < 14);
        fb[mi] = av ? (const char*)rawh + ((size_t)(b * 196 + iy * 14 + ix)) * 4096 + ks * 2048 : zpad;
        fs[mi] = av ? 1 : 0;
    }

    const char* gB = (const char*)Bh + (size_t)tap * 524288 + (size_t)ks * 262144 + lane * 16;

    floatx4 acc[4][8];
    const floatx4 fz = {0.f, 0.f, 0.f, 0.f};
    #pragma unroll
    for (int mi = 0; mi < 4; ++mi)
        #pragma unroll
        for (int j = 0; j < 8; ++j) acc[mi][j] = fz;

    half8 aC[8], aN[8];

    // prologue: stage B(0) -> buf0 + load A(0) (8+8 = 16 outstanding/wave)
    #pragma unroll
    for (int i = 0; i < 8; ++i)
        glds16(gB + (size_t)wv * 8192 + i * 1024, L + wv * 8192 + i * 1024);
    #pragma unroll
    for (int mi = 0; mi < 4; ++mi) {
        aC[mi * 2 + 0] = *(const half8*)(fb[mi] + fs[mi] * (quad * 16));
        aC[mi * 2 + 1] = *(const half8*)(fb[mi] + fs[mi] * (64 + quad * 16));
    }

    auto step = [&](int sn, const char* Lc, char* Ln, half8 (&ac)[8], half8 (&an)[8]) {
        #pragma unroll
        for (int i = 0; i < 8; ++i)
            glds16(gB + (size_t)(2 * sn + wv) * 8192 + i * 1024, Ln + wv * 8192 + i * 1024);
        #pragma unroll
        for (int mi = 0; mi < 4; ++mi) {
            an[mi * 2 + 0] = *(const half8*)(fb[mi] + fs[mi] * (sn * 128 + quad * 16));
            an[mi * 2 + 1] = *(const half8*)(fb[mi] + fs[mi] * (sn * 128 + 64 + quad * 16));
        }
        asm volatile("s_waitcnt vmcnt(16)" ::: "memory");
        __builtin_amdgcn_s_barrier();
        __builtin_amdgcn_sched_barrier(0);
        #pragma unroll
        for (int ki = 0; ki < 2; ++ki) {
            #pragma unroll
            for (int j = 0; j < 8; ++j) {
                half8 b = *(const half8*)(Lc + ki * 8192 + quad * 2048 + (j * 16 + lm) * 16);
                #pragma unroll
                for (int mi = 0; mi < 4; ++mi)
                    acc[mi][j] = __builtin_amdgcn_mfma_f32_16x16x32_f16(ac[mi * 2 + ki], b, acc[mi][j], 0, 0, 0);
            }
        }
        __builtin_amdgcn_sched_barrier(0);
        __builtin_amdgcn_s_barrier();
    };

    for (int h = 0; h < 8; ++h) {
        const int s1 = 2 * h + 1;
        step(s1, L, L + 16384, aC, aN);
        step((s1 < 15) ? s1 + 1 : 0, L + 16384, L, aN, aC);
    }

    if (tile >= 49) return;
    #pragma unroll
    for (int j = 0; j < 8; ++j) {
        const int n = j * 16 + lm;
        #pragma unroll
        for (int mi = 0; mi < 4; ++mi) {
            const int m0 = tile * 64 + mi * 16 + quad * 4;
            #pragma unroll
            for (int r = 0; r < 4; ++r)
                y1p[((size_t)tx * 3136 + m0 + r) * 128 + n] = acc[mi][j][r];
        }
    }
}

// ========= y1 reduce (18 slices) + bias + relu, fused with raw_mean =========
__global__ __launch_bounds__(256)
void y1r_rm(const float* __restrict__ y1p, const float* __restrict__ bias,
            float* __restrict__ y1,
            const half_t* __restrict__ rh, float* __restrict__ concat)
{
    if (blockIdx.x < 1568) {
        const int t = blockIdx.x * 256 + threadIdx.x;
        const int n = t & 127;
        float s = bias[n];
        #pragma unroll
        for (int ks = 0; ks < 18; ++ks) s += y1p[(size_t)ks * 3136 * 128 + t];
        y1[t] = fmaxf(s, 0.f);
    } else {
        const int t = (blockIdx.x - 1568) * 256 + threadIdx.x;
        const int n = t & 2047, b = (t >> 11) & 15, pc = t >> 15;
        float s = 0.f;
        const int p0 = pc * 49;
        for (int p = p0; p < p0 + 49; ++p)
            s += (float)rh[(size_t)(b * 196 + p) * 2048 + n];
        atomicAdd(concat + (size_t)b * 10240 + 8192 + n, s * (1.f / 196.f));
    }
}

// ================= tidy helper (wave per output) =================
__device__ __forceinline__ void tidy_one(const float* in, const float* wr, float bi,
                                         float* dst, int lane)
{
    float acc = in[lane] * wr[lane] + in[lane + 64] * wr[lane + 64];
    #pragma unroll
    for (int s = 32; s > 0; s >>= 1) acc += __shfl_down(acc, s, 64);
    if (lane == 0) *dst = acc + bi;
}

// ================= conv_s2 body =================
__device__ __forceinline__ void conv_s2_body(int t, const float* __restrict__ in,
                                             const float* __restrict__ wt,
                                             const float* __restrict__ bias,
                                             float* __restrict__ out, int Win, int Wout)
{
    const int oc = t & 127;
    const int pos = (t >> 7) % (Wout * Wout);
    const int b = t / (128 * Wout * Wout);
    if (b >= 16) return;
    const int oy = pos / Wout, ox = pos % Wout;
    float acc = bias[oc];
    for (int dy = 0; dy < 3; ++dy) {
        const int y = oy * 2 + dy - 1;
        if (y < 0 || y >= Win) continue;
        for (int dx = 0; dx < 3; ++dx) {
            const int x = ox * 2 + dx - 1;
            if (x < 0 || x >= Win) continue;
            const float* ip = in + (size_t)(b * Win * Win + y * Win + x) * 128;
            const float* wp = wt + (size_t)(dy * 3 + dx) * 16384 + oc;
            for (int ic = 0; ic < 128; ++ic)
                acc += ip[ic] * wp[ic * 128];
        }
    }
    out[(size_t)(b * Wout * Wout + pos) * 128 + oc] = fmaxf(acc, 0.f);
}

// ============ fused: conv_s2 y1->y2 (blocks 0..391)  ||  tidy level-1 (392..5095) ============
__global__ __launch_bounds__(256)
void conv2_tidy1(const float* __restrict__ y1, const float* __restrict__ wt2t,
                 const float* __restrict__ b2d, float* __restrict__ y2,
                 const float* __restrict__ w1t, const float* __restrict__ b1t,
                 float* __restrict__ scores)
{
    if (blockIdx.x < 392) {
        conv_s2_body(blockIdx.x * 256 + threadIdx.x, y1, wt2t, b2d, y2, 14, 7);
    } else {
        const int wid = (blockIdx.x - 392) * 4 + (threadIdx.x >> 6);
        const int lane = threadIdx.x & 63;
        if (wid >= 16 * 1176) return;
        const int b = wid / 1176, i1 = wid % 1176;
        const int ch = i1 / 196, pos = i1 % 196;
        tidy_one(y1 + (size_t)(b * 196 + pos) * 128, w1t + ch * 128, b1t[ch],
                 scores + b * 1614 + i1, lane);
    }
}

// ============ fused: conv_s2 y2->y3 (blocks 0..127)  ||  tidy level-2 (128..1303) ============
__global__ __launch_bounds__(256)
void conv3_tidy2(const float* __restrict__ y2, const float* __restrict__ wt3t,
                 const float* __restrict__ b3d, float* __restrict__ y3,
                 const float* __restrict__ w2t, const float* __restrict__ b2t,
                 float* __restrict__ scores)
{
    if (blockIdx.x < 128) {
        conv_s2_body(blockIdx.x * 256 + threadIdx.x, y2, wt3t, b3d, y3, 7, 4);
    } else {
        const int wid = (blockIdx.x - 128) * 4 + (threadIdx.x >> 6);
        const int lane = threadIdx.x & 63;
        if (wid >= 16 * 294) return;
        const int b = wid / 294, i2 = wid % 294;
        const int ch = i2 / 49, pos = i2 % 49;
        tidy_one(y2 + (size_t)(b * 49 + pos) * 128, w2t + ch * 128, b2t[ch],
                 scores + b * 1614 + 1176 + i2, lane);
    }
}

// ================= tidy level-3 =================
__global__ __launch_bounds__(256)
void tidy3(const float* __restrict__ y3, const float* __restrict__ w3t,
           const float* __restrict__ b3t, float* __restrict__ scores)
{
    const int wid = blockIdx.x * 4 + (threadIdx.x >> 6);
    const int lane = threadIdx.x & 63;
    if (wid >= 16 * 144) return;
    const int b = wid / 144, i3 = wid % 144;
    const int ch = i3 / 16, pos = i3 % 16;
    tidy_one(y3 + (size_t)(b * 16 + pos) * 128, w3t + ch * 128, b3t[ch],
             scores + b * 1614 + 1470 + i3, lane);
}

// ================= NMS: register-resident, shuffle reduce =================
__global__ __launch_bounds__(256)
void nms(const float* __restrict__ scores, const int* __restrict__ anchors,
         int* __restrict__ top_idx)
{
    __shared__ float wv_v[4];
    __shared__ int wv_i[4];
    __shared__ int s_pick;
    const int b = blockIdx.x, tid = threadIdx.x;
    const int lane = tid & 63, wv = tid >> 6;
    float sc[7], ay0[7], ax0[7], ay1[7], ax1[7];
    unsigned int vmask = 0;
    #pragma unroll
    for (int j = 0; j < 7; ++j) {
        const int i = tid + j * 256;
        if (i < 1614) {
            sc[j]  = scores[b * 1614 + i];
            ay0[j] = (float)anchors[i * 4 + 0];
            ax0[j] = (float)anchors[i * 4 + 1];
            ay1[j] = (float)anchors[i * 4 + 2];
            ax1[j] = (float)anchors[i * 4 + 3];
            vmask |= 1u << j;
        }
    }
    for (int r = 0; r < 4; ++r) {
        float bv = -INFINITY; int bi = 0x7fffffff;
        #pragma unroll
        for (int j = 0; j < 7; ++j) {
            if (vmask & (1u << j)) {
                const float v = sc[j];
                const int i = tid + j * 256;
                if (v > bv || (v == bv && i < bi)) { bv = v; bi = i; }
            }
        }
        #pragma unroll
        for (int s = 32; s > 0; s >>= 1) {
            const float v2 = __shfl_down(bv, s, 64);
            const int   i2 = __shfl_down(bi, s, 64);
            if (v2 > bv || (v2 == bv && i2 < bi)) { bv = v2; bi = i2; }
        }
        if (lane == 0) { wv_v[wv] = bv; wv_i[wv] = bi; }
        __syncthreads();
        if (tid == 0) {
            float fv = wv_v[0]; int fi = wv_i[0];
            #pragma unroll
            for (int k = 1; k < 4; ++k)
                if (wv_v[k] > fv || (wv_v[k] == fv && wv_i[k] < fi)) { fv = wv_v[k]; fi = wv_i[k]; }
            s_pick = fi;
            top_idx[b * 4 + r] = fi;
        }
        __syncthreads();
        const int pick = s_pick;
        const float py0 = (float)anchors[pick * 4 + 0], px0 = (float)anchors[pick * 4 + 1];
        const float py1 = (float)anchors[pick * 4 + 2], px1 = (float)anchors[pick * 4 + 3];
        const float pa = (py1 - py0) * (px1 - px0);
        #pragma unroll
        for (int j = 0; j < 7; ++j) {
            if (vmask & (1u << j)) {
                const float ih = fminf(ay1[j], py1) - fmaxf(ay0[j], py0);
                const float iw = fminf(ax1[j], px1) - fmaxf(ax0[j], px0);
                const float inter = (ih < 0.f || iw < 0.f) ? 0.f : ih * iw;
                const float area = (ay1[j] - ay0[j]) * (ax1[j] - ax0[j]);
                const float iou = inter / ((area + pa) - inter);
                if (iou >= 0.25f) vmask &= ~(1u << j);
            }
        }
    }
}

// ================= crop_mean =================
__global__ __launch_bounds__(256)
void crop_mean(const float* __restrict__ x, const int* __restrict__ anchors,
               const int* __restrict__ top_idx, float* __restrict__ abar)
{
    __shared__ float red[256];
    const int bi = blockIdx.x;               // 6144
    const int q = bi / 96, rem = bi % 96, c = rem >> 5, r = rem & 31;
    const int tid = threadIdx.x;
    const int cc = tid & 31, ps = tid >> 5;
    const int idx = top_idx[q];
    const int y0 = anchors[idx * 4 + 0], x0 = anchors[idx * 4 + 1];
    const int y1 = anchors[idx * 4 + 2], x1 = anchors[idx * 4 + 3];
    const float hh = (float)(y1 - y0), ww = (float)(x1 - x0);
    const float* xb = x + (size_t)((q >> 2) * 3 + c) * 200704;
    float acc = 0.f;
    for (int p = ps; p < 49; p += 8) {
        const int oy = p / 7, ox = p % 7;
        const int typ = oy * 32 + r;
        const int txp = ox * 32 + cc;
        const float sy = (float)typ * (hh - 1.0f) / 223.0f;
        const float fy = floorf(sy);
        const float wy = sy - fy;
        const int iy0 = y0 + (int)fy;
        const int iy1 = min(iy0 + 1, y1 - 1);
        const float sx = (float)txp * (ww - 1.0f) / 223.0f;
        const float fx = floorf(sx);
        const float wx = sx - fx;
        const int ix0 = x0 + (int)fx;
        const int ix1 = min(ix0 + 1, x1 - 1);
        const int ry0 = iy0 - 224, ry1 = iy1 - 224;
        const int rx0 = ix0 - 224, rx1 = ix1 - 224;
        const bool vy0 = (ry0 >= 0 && ry0 < 448), vy1 = (ry1 >= 0 && ry1 < 448);
        const bool vx0 = (rx0 >= 0 && rx0 < 448), vx1 = (rx1 >= 0 && rx1 < 448);
        const float v00 = (vy0 && vx0) ? xb[(size_t)ry0 * 448 + rx0] : 0.f;
        const float v01 = (vy0 && vx1) ? xb[(size_t)ry0 * 448 + rx1] : 0.f;
        const float v10 = (vy1 && vx0) ? xb[(size_t)ry1 * 448 + rx0] : 0.f;
        const float v11 = (vy1 && vx1) ? xb[(size_t)ry1 * 448 + rx1] : 0.f;
        const float top = v00 * (1.f - wx) + v01 * wx;
        const float bot = v10 * (1.f - wx) + v11 * wx;
        acc += top * (1.f - wy) + bot * wy;
    }
    red[tid] = acc;
    __syncthreads();
    if (tid < 32) {
        float s = 0.f;
        #pragma unroll
        for (int k = 0; k < 8; ++k) s += red[tid + 32 * k];
        abar[(size_t)q * 3072 + c * 1024 + r * 32 + cc] = s * (1.f / 49.f);
    }
}

// ================= part_gemm =================
__global__ __launch_bounds__(256)
void part_gemm(const float* __restrict__ abar, const half_t* __restrict__ Bh,
               float* __restrict__ concat)
{
    __shared__ __align__(16) char L[12288];
    const int tid = threadIdx.x, lane = tid & 63, wv = tid >> 6;
    const int lm = lane & 15, quad = lane >> 4;
    const int nt = blockIdx.x, ks = blockIdx.y;
    const char* gBh = (const char*)Bh + ((size_t)nt * 96 + ks * 12) * 4096 + lane * 16;
    const int am = tid & 63, akg = tid >> 6;

    floatx4 acc[4], accl[4];
    const floatx4 fz = {0.f, 0.f, 0.f, 0.f};
    #pragma unroll
    for (int j = 0; j < 4; ++j) { acc[j] = fz; accl[j] = fz; }

    for (int s = 0; s < 12; ++s) {
        {
            const float* pa = abar + (size_t)am * 3072 + (ks * 12 + s) * 32 + akg * 8;
            float f[8];
            *(float4*)&f[0] = *(const float4*)pa;
            *(float4*)&f[4] = *(const float4*)(pa + 4);
            half8 h, l;
            #pragma unroll
            for (int j = 0; j < 8; ++j) {
                const half_t hh = (half_t)f[j];
                h[j] = hh;
                l[j] = (half_t)(f[j] - (float)hh);
            }
            *(half8*)(L + (akg * 64 + am) * 16) = h;
            *(half8*)(L + 4096 + (akg * 64 + am) * 16) = l;
        }
        glds16(gBh + (size_t)s * 4096 + wv * 1024, L + 8192 + wv * 1024);
        __syncthreads();
        half8 ah, al, bh[4];
        ah = *(const half8*)(L + (quad * 64 + wv * 16 + lm) * 16);
        al = *(const half8*)(L + 4096 + (quad * 64 + wv * 16 + lm) * 16);
        #pragma unroll
        for (int j = 0; j < 4; ++j) bh[j] = *(const half8*)(L + 8192 + (quad * 64 + j * 16 + lm) * 16);
        #pragma unroll
        for (int j = 0; j < 4; ++j) {
            acc[j]  = __builtin_amdgcn_mfma_f32_16x16x32_f16(ah, bh[j], acc[j], 0, 0, 0);
            accl[j] = __builtin_amdgcn_mfma_f32_16x16x32_f16(al, bh[j], accl[j], 0, 0, 0);
        }
        __syncthreads();
    }
    #pragma unroll
    for (int j = 0; j < 4; ++j) {
        const int n = nt * 64 + j * 16 + lm;
        #pragma unroll
        for (int r = 0; r < 4; ++r) {
            const int m = wv * 16 + quad * 4 + r;
            atomicAdd(concat + (size_t)(m >> 2) * 10240 + (m & 3) * 2048 + n,
                      acc[j][r] + accl[j][r]);
        }
    }
}

// ================= classifier GEMM =================
__global__ __launch_bounds__(256)
void cls_gemm(const float* __restrict__ concat, const float* __restrict__ w,
              float* __restrict__ out)
{
    __shared__ float ws_[8 * 321];
    __shared__ float cs_[16 * 321];
    __shared__ float red[256];
    const int nchunk = blockIdx.x, ks = blockIdx.y;
    const int tid = threadIdx.x;
    for (int i = tid; i < 2560; i += 256) {
        const int r = i / 320, k = i % 320;
        ws_[r * 321 + k] = w[(size_t)(nchunk * 8 + r) * 10240 + ks * 320 + k];
    }
    for (int i = tid; i < 5120; i += 256) {
        const int r = i / 320, k = i % 320;
        cs_[r * 321 + k] = concat[(size_t)r * 10240 + ks * 320 + k];
    }
    __syncthreads();
    const int b = tid & 15, c = (tid >> 4) & 7, hf = tid >> 7;
    const float* cp = cs_ + b * 321 + hf * 160;
    const float* wp = ws_ + c * 321 + hf * 160;
    float a = 0.f;
    #pragma unroll 8
    for (int k = 0; k < 160; ++k) a += cp[k] * wp[k];
    red[tid] = a;
    __syncthreads();
    if (tid < 128) atomicAdd(out + b * 200 + nchunk * 8 + c, red[tid] + red[tid + 128]);
}

extern "C" void kernel_launch(void* const* d_in, const int* in_sizes, int n_in,
                              void* d_out, int out_size, void* d_ws, size_t ws_size,
                              hipStream_t stream)
{
    const float* x     = (const float*)d_in[0];
    const float* bb_w  = (const float*)d_in[1];
    const float* bb_b  = (const float*)d_in[2];
    const float* n1_dw = (const float*)d_in[3];
    const float* n1_db = (const float*)d_in[4];
    const float* n1_tw = (const float*)d_in[5];
    const float* n1_tb = (const float*)d_in[6];
    const float* n2_dw = (const float*)d_in[7];
    const float* n2_db = (const float*)d_in[8];
    const float* n2_tw = (const float*)d_in[9];
    const float* n2_tb = (const float*)d_in[10];
    const float* n3_dw = (const float*)d_in[11];
    const float* n3_db = (const float*)d_in[12];
    const float* n3_tw = (const float*)d_in[13];
    const float* n3_tb = (const float*)d_in[14];
    const float* cn_w  = (const float*)d_in[15];
    const float* cn_b  = (const float*)d_in[16];
    const int*   anchors = (const int*)d_in[17];
    float* out = (float*)d_out;
    char* W = (char*)d_ws;

    half_t* bbwh  = (half_t*)(W + 0);
    float*  zpad  = (float*)(W + 12582912);
    int*    topidx= (int*)(W + 12583936);
    float*  scores= (float*)(W + 12584960);
    float*  y1    = (float*)(W + 12688384);
    float*  y2    = (float*)(W + 14294016);
    float*  y3    = (float*)(W + 14695424);
    float*  concat= (float*)(W + 14826496);
    half_t* w1h   = (half_t*)(W + 15481856);
    float*  wt2t  = (float*)(W + 20200448);
    float*  wt3t  = (float*)(W + 20790272);
    char* E = W + 21380096;
    half_t* xh    = (half_t*)E;
    float*  y1p   = (float*)E;      // alias: xh dead after gemm_x
    char* F = W + 60701696;
    half_t* rawh  = (half_t*)F;
    float*  abar  = (float*)F;      // alias: raw dead after gemm_nav + y1r_rm

    prep_all<<<3902, 256, 0, stream>>>(x, bb_w, n1_dw, n2_dw, n3_dw, cn_b, bb_b,
                                       xh, bbwh, w1h, wt2t, wt3t, out, zpad, concat);

    gemm_x<<<dim3(16, 49), 128, 0, stream>>>(xh, bbwh, bb_b, rawh);
    gemm_nav<<<dim3(18, 25), 128, 0, stream>>>(rawh, w1h, (const char*)zpad, y1p);
    y1r_rm<<<2080, 256, 0, stream>>>(y1p, n1_db, y1, rawh, concat);

    conv2_tidy1<<<5096, 256, 0, stream>>>(y1, wt2t, n2_db, y2, n1_tw, n1_tb, scores);
    conv3_tidy2<<<1304, 256, 0, stream>>>(y2, wt3t, n3_db, y3, n2_tw, n2_tb, scores);
    tidy3<<<576, 256, 0, stream>>>(y3, n3_tw, n3_tb, scores);

    nms<<<16, 256, 0, stream>>>(scores, anchors, topidx);
    crop_mean<<<6144, 256, 0, stream>>>(x, anchors, topidx, abar);

    part_gemm<<<dim3(32, 8), 256, 0, stream>>>(abar, bbwh, concat);
    cls_gemm<<<dim3(25, 32), 256, 0, stream>>>(concat, cn_w, out);
}